// Round 17
// baseline (1155.756 us; speedup 1.0000x reference)
//
#include <hip/hip_runtime.h>
#include <math.h>

// Performer (FAVOR+) forward, 6 layers. bf16 MFMA + global_load_lds staging.
// Round 16: k_dv fused into k_ln_qkv (diag via shfl reduce, vsum as chunk
// partials reduced in k_fin_ctx); o stored/read as bf16. 6 kernels/layer.
// B=8 N=4096 DIM=3 H=3 DH=128 INNER=384 M=620(pad 640) FF=12
#define B_ 8
#define N_ 4096
#define H_ 3
#define DH_ 128
#define INNER_ 384
#define M_ 620
#define MP_ 640
#define DEPTH_ 6
#define BH_ 24

static constexpr float DN_ = 0.29730177875068026f;     // 128^-0.25
static constexpr float RATIO_ = 0.04016096644512494f;  // 620^-0.5
static constexpr float EPS_ = 1e-4f;

typedef __attribute__((ext_vector_type(8))) short short8;
typedef __attribute__((ext_vector_type(4))) float f32x4;

__device__ __forceinline__ short f2bf(float f) {
  union { float f; unsigned u; } x; x.f = f;
  unsigned r = x.u + 0x7FFF + ((x.u >> 16) & 1);
  return (short)(r >> 16);
}
__device__ __forceinline__ float bf2f(short s) {
  union { unsigned u; float f; } x; x.u = ((unsigned)(unsigned short)s) << 16;
  return x.f;
}
__device__ __forceinline__ float4 ldg4(const float* p) { return *(const float4*)p; }

// packed f32x2 -> bf16x2 (RNE), one VALU op
__device__ __forceinline__ unsigned cvtpk(float lo, float hi) {
  unsigned r;
  asm("v_cvt_pk_bf16_f32 %0, %1, %2" : "=v"(r) : "v"(lo), "v"(hi));
  return r;
}

// async global->LDS DMA, 16B per lane. LDS dest = uniform base + lane*16.
__device__ __forceinline__ void gl2lds(const void* g, void* l) {
  __builtin_amdgcn_global_load_lds(
      (const __attribute__((address_space(1))) void*)g,
      (__attribute__((address_space(3))) void*)l, 16, 0, 0);
}

// stage a 32-row x 256B tile, 8 waves (one DMA/lane). read back with:
// ofs = row*256 + (want ^ ((row&7)<<4))
__device__ __forceinline__ void stage_t256(const char* gbase, char* lds, int w, int l) {
  int row = w * 4 + (l >> 4);
  int col = ((l & 15) * 16) ^ ((row & 7) << 4);
  char* lp = lds + __builtin_amdgcn_readfirstlane(w << 10);
  gl2lds(gbase + row * 256 + col, lp);
}

// stage a 128-row x 64B tile (row stride growb bytes), 8 waves, swizzle
// sw64(d) = ((d ^ (d>>2)) & 3) << 4. read back: ofs = d*64 + (want ^ sw64(d))
__device__ __forceinline__ void stage_t64(const char* gbase, size_t growb, char* lds,
                                          int w, int l) {
  int d = w * 16 + (l >> 2);
  int swl = ((((l >> 2) ^ (l >> 4)) & 3) << 4);  // == sw64(d) for this lane
  int col = ((l & 3) * 16) ^ swl;
  char* lp = lds + __builtin_amdgcn_readfirstlane(w << 10);
  gl2lds(gbase + (size_t)d * growb + col, lp);
}

// ---------------------------------------------------------------- copy
__global__ void k_copy(const float* __restrict__ s, float* __restrict__ d, int n) {
  int i = blockIdx.x * 256 + threadIdx.x;
  if (i < n) d[i] = s[i];
}

// ------------------------------------------- proj -> bf16, padded to 640 rows
__global__ void k_projcvt(const float* __restrict__ proj, short* __restrict__ pb) {
  int i = blockIdx.x * 256 + threadIdx.x;
  if (i >= DEPTH_ * MP_ * DH_) return;
  int l = i / (MP_ * DH_);
  int rem = i - l * (MP_ * DH_);
  int m = rem >> 7, d = rem & 127;
  pb[i] = (m < M_) ? f2bf(proj[((size_t)l * M_ + m) * DH_ + d]) : (short)0;
}

// ---------- LN1 + QKV; 32 tokens/block; emits q,k row-major, v transposed+
// pi-permuted into vtp, diag_k (shfl reduce), and vsum chunk partials.
__global__ __launch_bounds__(384) void k_ln_qkv(
    const float* __restrict__ x, const float* __restrict__ Wq,
    const float* __restrict__ Wk, const float* __restrict__ Wv,
    const float* __restrict__ g1, const float* __restrict__ b1,
    short* __restrict__ qb, short* __restrict__ kb, short* __restrict__ vtp,
    float* __restrict__ diag_k, float* __restrict__ vsppart) {
  __shared__ float xs[96];
  __shared__ float wred[6][32];
  int c = threadIdx.x;
  int token0 = blockIdx.x * 32;
  int b = token0 >> 12, n0 = token0 & 4095;
  if (c < 96) xs[c] = x[(size_t)token0 * 3 + c];
  float wq0 = Wq[c], wq1 = Wq[INNER_ + c], wq2 = Wq[2 * INNER_ + c];
  float wk0 = Wk[c], wk1 = Wk[INNER_ + c], wk2 = Wk[2 * INNER_ + c];
  float wv0 = Wv[c], wv1 = Wv[INNER_ + c], wv2 = Wv[2 * INNER_ + c];
  float G0 = g1[0], G1 = g1[1], G2 = g1[2];
  float B0 = b1[0], B1 = b1[1], B2 = b1[2];
  int hh = c >> 7, dh = c & 127;
  int w = c >> 6;
  size_t rowbase = ((size_t)(b * H_ + hh) * N_ + n0) * DH_ + dh;
  __syncthreads();
  short8 v8[4];
  float vsum_acc = 0.f;
#pragma unroll
  for (int tt = 0; tt < 32; ++tt) {
    float x0 = xs[tt * 3], x1 = xs[tt * 3 + 1], x2 = xs[tt * 3 + 2];
    float mu = (x0 + x1 + x2) * (1.f / 3.f);
    float d0 = x0 - mu, d1 = x1 - mu, d2 = x2 - mu;
    float rs = rsqrtf((d0 * d0 + d1 * d1 + d2 * d2) * (1.f / 3.f) + 1e-5f);
    float h0 = d0 * rs * G0 + B0;
    float h1 = d1 * rs * G1 + B1;
    float h2 = d2 * rs * G2 + B2;
    qb[rowbase + (size_t)tt * DH_] = f2bf((h0 * wq0 + h1 * wq1 + h2 * wq2) * DN_);
    short kbs = f2bf((h0 * wk0 + h1 * wk1 + h2 * wk2) * DN_);
    kb[rowbase + (size_t)tt * DH_] = kbs;
    float kvr = bf2f(kbs);
    float kk = kvr * kvr;
#pragma unroll
    for (int off = 32; off; off >>= 1) kk += __shfl_xor(kk, off);
    if ((c & 63) == 0) wred[w][tt] = kk;
    short vbs = f2bf(h0 * wv0 + h1 * wv1 + h2 * wv2);
    vsum_acc += bf2f(vbs);
    const int p = ((tt >> 2) & 3) * 8 + ((tt >> 4) & 1) * 4 + (tt & 3);
    v8[p >> 3][p & 7] = vbs;
  }
  short* dst = vtp + ((size_t)(b * H_ + hh) * DH_ + dh) * N_ + n0;
  *(short8*)dst = v8[0];
  *(short8*)(dst + 8) = v8[1];
  *(short8*)(dst + 16) = v8[2];
  *(short8*)(dst + 24) = v8[3];
  vsppart[((size_t)(b * H_ + hh) * DH_ + dh) * 128 + (n0 >> 5)] = vsum_acc;
  __syncthreads();
  if (c < 96) {
    int h2 = c >> 5, tt = c & 31;
    diag_k[(size_t)(b * H_ + h2) * N_ + n0 + tt] =
        0.5f * (wred[2 * h2][tt] + wred[2 * h2 + 1][tt]);
  }
}

// ------------- key features -> ctx partials (K,Vt via LDS double-buffer,
// PAIR-CHUNKED: 2 n-chunks per barrier period, 16 barriers total).
// grid (4 ns, 5 mt, 24 bh), 512 threads. Per-wave ONLINE max (exact).
__global__ __launch_bounds__(512) void k_kp_ctx(
    const short* __restrict__ kb, const short* __restrict__ vtp,
    const short* __restrict__ pb, const float* __restrict__ diag_k,
    float* __restrict__ Cpart, float* __restrict__ spart,
    float* __restrict__ bmx) {
  int ns = blockIdx.x, mt = blockIdx.y, bh = blockIdx.z;
  __shared__ __align__(16) char Ks[2][16384];
  __shared__ __align__(16) char Vts[2][16384];
  __shared__ float diag_s[1024];
  int t = threadIdx.x, w = t >> 6, l = t & 63, lr = l & 15, lg = l >> 4;
  {
    const float* dbase = diag_k + (size_t)bh * N_ + ns * 1024;
#pragma unroll
    for (int i = 0; i < 2; ++i) diag_s[t + i * 512] = dbase[t + i * 512];
  }
  int m0 = mt * 128 + w * 16;
  short8 bfr[4];
  {
    const short* pr = pb + (size_t)(m0 + lr) * DH_ + lg * 8;
#pragma unroll
    for (int ks = 0; ks < 4; ++ks) bfr[ks] = *(const short8*)(pr + ks * 32);
  }
  const char* kgb = (const char*)(kb + ((size_t)bh * N_ + ns * 1024) * DH_);
  const char* vgb = (const char*)(vtp + (size_t)bh * DH_ * N_ + ns * 1024);
  stage_t256(kgb, Ks[0], w, l);
  stage_t256(kgb + 32 * 256, Ks[0] + 8192, w, l);
  stage_t64(vgb, (size_t)N_ * 2, Vts[0], w, l);
  stage_t64(vgb + 64, (size_t)N_ * 2, Vts[0] + 8192, w, l);
  __syncthreads();
  f32x4 cacc[8];
#pragma unroll
  for (int db = 0; db < 8; ++db) cacc[db] = (f32x4){0.f, 0.f, 0.f, 0.f};
  float ksacc = 0.f;
  float bm = -INFINITY;  // wave-uniform running max of valid dd
  const bool mv = (m0 + lr) < M_;
  int xk = (lr & 7) << 4;
  int xv = ((lr ^ (lr >> 2)) & 3) << 4;  // sw64(db*16+lr), db-independent
  for (int pc = 0; pc < 16; ++pc) {
    int cur = pc & 1;
    if (pc < 15) {
      const char* kc = kgb + (size_t)(2 * pc + 2) * 32 * 256;
      stage_t256(kc, Ks[cur ^ 1], w, l);
      stage_t256(kc + 32 * 256, Ks[cur ^ 1] + 8192, w, l);
      const char* vc = vgb + (size_t)(2 * pc + 2) * 64;
      stage_t64(vc, (size_t)N_ * 2, Vts[cur ^ 1], w, l);
      stage_t64(vc + 64, (size_t)N_ * 2, Vts[cur ^ 1] + 8192, w, l);
    }
#pragma unroll
    for (int sub = 0; sub < 2; ++sub) {
      const char* KS = Ks[cur] + sub * 8192;
      const char* VS = Vts[cur] + sub * 8192;
      int n0 = (2 * pc + sub) * 32;
      f32x4 dd[2];
      __builtin_amdgcn_s_setprio(1);
#pragma unroll
      for (int nsub = 0; nsub < 2; ++nsub) {
        f32x4 acc = {0.f, 0.f, 0.f, 0.f};
#pragma unroll
        for (int ks = 0; ks < 4; ++ks)
          acc = __builtin_amdgcn_mfma_f32_16x16x32_bf16(
              *(const short8*)(KS + (nsub * 16 + lr) * 256 +
                               ((lg * 16 + ks * 64) ^ xk)),
              bfr[ks], acc, 0, 0, 0);
        dd[nsub] = acc;
      }
      __builtin_amdgcn_s_setprio(0);
      // wave-uniform online max over valid m (6-step xor reduce)
      float cm = -INFINITY;
      if (mv) {
#pragma unroll
        for (int nsub = 0; nsub < 2; ++nsub)
#pragma unroll
          for (int rg = 0; rg < 4; ++rg) cm = fmaxf(cm, dd[nsub][rg]);
      }
#pragma unroll
      for (int off = 1; off < 64; off <<= 1) cm = fmaxf(cm, __shfl_xor(cm, off));
      if (cm > bm) {  // wave-uniform
        float sc = __expf(bm - cm);  // 0 on first trigger
        bm = cm;
        ksacc *= sc;
#pragma unroll
        for (int db = 0; db < 8; ++db)
#pragma unroll
          for (int rg = 0; rg < 4; ++rg) cacc[db][rg] *= sc;
      }
      float ev[8];
#pragma unroll
      for (int nsub = 0; nsub < 2; ++nsub)
#pragma unroll
        for (int rg = 0; rg < 4; ++rg) {
          float e = __expf(dd[nsub][rg] - diag_s[n0 + nsub * 16 + 4 * lg + rg] - bm);
          ev[nsub * 4 + rg] = e;
          ksacc += e;
        }
      union { short8 s8; unsigned u[4]; } ea;
#pragma unroll
      for (int i = 0; i < 4; ++i) ea.u[i] = cvtpk(ev[2 * i], ev[2 * i + 1]);
      __builtin_amdgcn_s_setprio(1);
#pragma unroll
      for (int db = 0; db < 8; ++db)
        cacc[db] = __builtin_amdgcn_mfma_f32_16x16x32_bf16(
            ea.s8, *(const short8*)(VS + (db * 16 + lr) * 64 + ((lg * 16) ^ xv)),
            cacc[db], 0, 0, 0);
      __builtin_amdgcn_s_setprio(0);
    }
    __syncthreads();
  }
  float* Cp = Cpart + ((size_t)ns * BH_ + bh) * MP_ * DH_;
#pragma unroll
  for (int db = 0; db < 8; ++db) {
    int d = db * 16 + lr;
#pragma unroll
    for (int rg = 0; rg < 4; ++rg)
      Cp[(size_t)(m0 + 4 * lg + rg) * DH_ + d] = cacc[db][rg];
  }
  ksacc += __shfl_down(ksacc, 32);
  ksacc += __shfl_down(ksacc, 16);
  if (l < 16) spart[((size_t)ns * BH_ + bh) * MP_ + m0 + l] = ksacc;
  if (l == 0) bmx[((size_t)ns * BH_ + bh) * 40 + mt * 8 + w] = bm;
}

// ------ finalize ctx: weighted merge of 4 ns partials (exp(bm-mx)) + EPS*vsum
// (reduced from chunk partials), emit pi-permuted bf16 ctxtp tile + colsum
// partial. mx reduced inline. grid (20 mt, 24 bh), 256 threads.
__global__ __launch_bounds__(256) void k_fin_ctx(
    const float* __restrict__ Cpart, const float* __restrict__ vsppart,
    const float* __restrict__ bmx,
    short* __restrict__ ctxtp, float* __restrict__ cspart) {
  int mt = blockIdx.x, bh = blockIdx.y;
  __shared__ float vsv[128];
  __shared__ short tile[128][40];
  __shared__ float redm[4];
  int t = threadIdx.x;
  if (t < 128) {
    const float* vp = vsppart + ((size_t)bh * DH_ + t) * 128;
    float s = 0.f;
#pragma unroll 8
    for (int i = 0; i < 128; ++i) s += vp[i];
    vsv[t] = s * EPS_;
  }
  float v = -INFINITY;
  if (t < 160) {
    int nsg = t / 40, g = t - nsg * 40;
    v = bmx[((size_t)nsg * BH_ + bh) * 40 + g];
  }
#pragma unroll
  for (int off = 32; off; off >>= 1) v = fmaxf(v, __shfl_xor(v, off));
  if ((t & 63) == 0) redm[t >> 6] = v;
  __syncthreads();
  float mxg = fmaxf(fmaxf(redm[0], redm[1]), fmaxf(redm[2], redm[3]));
  int r = t >> 3, seg = t & 7;
  int d0 = seg * 16;
  int m = mt * 32 + r;
  int p = ((r >> 2) & 3) * 8 + ((r >> 4) & 1) * 4 + (r & 3);
  const size_t ph = (size_t)BH_ * MP_ * DH_;
  const float* c0 = Cpart + (size_t)bh * MP_ * DH_ + (size_t)m * DH_ + d0;
  if (m < M_) {
    int g = m >> 4;
    float sc0 = __expf(bmx[((size_t)0 * BH_ + bh) * 40 + g] - mxg);
    float sc1 = __expf(bmx[((size_t)1 * BH_ + bh) * 40 + g] - mxg);
    float sc2 = __expf(bmx[((size_t)2 * BH_ + bh) * 40 + g] - mxg);
    float sc3 = __expf(bmx[((size_t)3 * BH_ + bh) * 40 + g] - mxg);
#pragma unroll
    for (int j4 = 0; j4 < 4; ++j4) {
      float4 a = ldg4(c0 + j4 * 4);
      float4 b = ldg4(c0 + ph + j4 * 4);
      float4 c = ldg4(c0 + 2 * ph + j4 * 4);
      float4 e = ldg4(c0 + 3 * ph + j4 * 4);
      float vals[4] = {sc0 * a.x + sc1 * b.x + sc2 * c.x + sc3 * e.x,
                       sc0 * a.y + sc1 * b.y + sc2 * c.y + sc3 * e.y,
                       sc0 * a.z + sc1 * b.z + sc2 * c.z + sc3 * e.z,
                       sc0 * a.w + sc1 * b.w + sc2 * c.w + sc3 * e.w};
#pragma unroll
      for (int j = 0; j < 4; ++j) {
        int d = d0 + j4 * 4 + j;
        tile[d][p] = f2bf(RATIO_ * (vals[j] + vsv[d]));
      }
    }
  } else {
#pragma unroll
    for (int j = 0; j < 16; ++j) tile[d0 + j][p] = 0;
  }
  __syncthreads();
  int d = t >> 1, half = t & 1;
  short* dst = ctxtp + ((size_t)bh * DH_ + d) * MP_ + mt * 32 + half * 16;
  short8 s0 = *(const short8*)&tile[d][half * 16];
  short8 s1 = *(const short8*)&tile[d][half * 16 + 8];
  *(short8*)dst = s0;
  *(short8*)(dst + 8) = s1;
  float cs = 0.f;
#pragma unroll
  for (int j = 0; j < 8; ++j) cs += bf2f(s0[j]) + bf2f(s1[j]);
  cs += __shfl_xor(cs, 1);
  if (half == 0) cspart[((size_t)bh * 20 + mt) * DH_ + d] = cs;
}

// ------ small finalize: ctxsum, weighted ksum merge (mx inline), ksum_pb
__global__ __launch_bounds__(128) void k_fin2(
    const float* __restrict__ cspart, const float* __restrict__ spart,
    const float* __restrict__ bmx,
    float* __restrict__ ctxsum, short* __restrict__ ksum_pb,
    float* __restrict__ ksumtot) {
  int bh = blockIdx.x, d = threadIdx.x;
  __shared__ float redm[2];
  float v = -INFINITY;
  for (int i = d; i < 160; i += 128) {
    int nsg = i / 40, g = i - nsg * 40;
    v = fmaxf(v, bmx[((size_t)nsg * BH_ + bh) * 40 + g]);
  }
#pragma unroll
  for (int off = 32; off; off >>= 1) v = fmaxf(v, __shfl_xor(v, off));
  if ((d & 63) == 0) redm[d >> 6] = v;
  float s = 0.f;
#pragma unroll
  for (int mt = 0; mt < 20; ++mt) s += cspart[((size_t)bh * 20 + mt) * DH_ + d];
  ctxsum[bh * DH_ + d] = s;
  __syncthreads();
  float mxg = fmaxf(redm[0], redm[1]);
  __shared__ float red[128];
  float kt = 0.f;
  for (int m = d; m < MP_; m += 128) {
    float ks = 0.f;
    if (m < M_) {
      size_t o = (size_t)bh * MP_ + m;
      size_t sh = (size_t)BH_ * MP_;
      int g = m >> 4;
      float s0 = __expf(bmx[((size_t)0 * BH_ + bh) * 40 + g] - mxg);
      float s1 = __expf(bmx[((size_t)1 * BH_ + bh) * 40 + g] - mxg);
      float s2 = __expf(bmx[((size_t)2 * BH_ + bh) * 40 + g] - mxg);
      float s3 = __expf(bmx[((size_t)3 * BH_ + bh) * 40 + g] - mxg);
      ks = RATIO_ * (s0 * spart[o] + s1 * spart[o + sh] + s2 * spart[o + 2 * sh] +
                     s3 * spart[o + 3 * sh] + EPS_ * (float)N_);
    }
    int r = m & 31;
    int p = ((r >> 2) & 3) * 8 + ((r >> 4) & 1) * 4 + (r & 3);
    ksum_pb[(size_t)bh * MP_ + (m & ~31) + p] = f2bf(ks);
    kt += ks;
  }
  red[d] = kt;
  __syncthreads();
  for (int st = 64; st > 0; st >>= 1) {
    if (d < st) red[d] += red[d + st];
    __syncthreads();
  }
  if (d == 0) ksumtot[bh] = red[0];
}

// -------- query side: online softmax (defer-rescale), den via MFMA,
// cvt_pk packing, bf16 output. grid (32 nt, 24 bh), 512 threads.
__global__ __launch_bounds__(512) void k_q_attn(
    const short* __restrict__ qb, const short* __restrict__ pb,
    const short* __restrict__ ctxtp, const short* __restrict__ ksum_pb,
    const float* __restrict__ ctxsum, const float* __restrict__ ksumtot,
    short* __restrict__ o) {
  int nt = blockIdx.x, bh = blockIdx.y;
  __shared__ __align__(16) char Pj[2][8192];
  __shared__ __align__(16) char Ct[2][8192];
  __shared__ __align__(16) short kslp[MP_];
  int t = threadIdx.x, w = t >> 6, l = t & 63, lr = l & 15, lg = l >> 4;
  if (t < MP_ / 8)
    ((short8*)kslp)[t] = ((const short8*)(ksum_pb + (size_t)bh * MP_))[t];
  const short* qr = qb + ((size_t)bh * N_ + nt * 128 + w * 16 + lr) * DH_ + lg * 8;
  short8 qfr[4];
#pragma unroll
  for (int ks = 0; ks < 4; ++ks) qfr[ks] = *(const short8*)(qr + ks * 32);
  // diag_q from fragments (bf16-consistent)
  float dq;
  {
    float s2 = 0.f;
#pragma unroll
    for (int ks = 0; ks < 4; ++ks)
#pragma unroll
      for (int j = 0; j < 8; ++j) {
        float v = bf2f(qfr[ks][j]);
        s2 = fmaf(v, v, s2);
      }
    s2 += __shfl_xor(s2, 16);
    s2 += __shfl_xor(s2, 32);
    dq = 0.5f * s2;
  }
  const char* cgb = (const char*)(ctxtp + (size_t)bh * DH_ * MP_);
  stage_t256((const char*)pb, Pj[0], w, l);
  stage_t64(cgb, (size_t)MP_ * 2, Ct[0], w, l);
  __syncthreads();
  f32x4 cacc[8];
#pragma unroll
  for (int db = 0; db < 8; ++db) cacc[db] = (f32x4){0.f, 0.f, 0.f, 0.f};
  f32x4 dacc = {0.f, 0.f, 0.f, 0.f};
  float om = -INFINITY;
  int xk = (lr & 7) << 4;
  int xv = ((lr ^ (lr >> 2)) & 3) << 4;  // sw64(db*16+lr), db-independent
  for (int mc = 0; mc < 20; ++mc) {
    int cur = mc & 1;
    if (mc < 19) {
      stage_t256((const char*)(pb + (size_t)(mc + 1) * 32 * DH_), Pj[cur ^ 1], w, l);
      stage_t64(cgb + (size_t)(mc + 1) * 64, (size_t)MP_ * 2, Ct[cur ^ 1], w, l);
    }
    int m0 = mc * 32;
    f32x4 qk[2];
    __builtin_amdgcn_s_setprio(1);
#pragma unroll
    for (int ms = 0; ms < 2; ++ms) {
      f32x4 acc = {0.f, 0.f, 0.f, 0.f};
#pragma unroll
      for (int ks = 0; ks < 4; ++ks)
        acc = __builtin_amdgcn_mfma_f32_16x16x32_bf16(
            *(const short8*)(Pj[cur] + (ms * 16 + lr) * 256 +
                             ((lg * 16 + ks * 64) ^ xk)),
            qfr[ks], acc, 0, 0, 0);
      qk[ms] = acc;
    }
    __builtin_amdgcn_s_setprio(0);
    // chunk row-max (rows n = lr; reduce across lg lane groups)
    float cm = -INFINITY;
#pragma unroll
    for (int ms = 0; ms < 2; ++ms)
#pragma unroll
      for (int rg = 0; rg < 4; ++rg) {
        int mg = m0 + ms * 16 + 4 * lg + rg;
        if (mg < M_) cm = fmaxf(cm, qk[ms][rg]);
      }
    cm = fmaxf(cm, __shfl_xor(cm, 16));
    cm = fmaxf(cm, __shfl_xor(cm, 32));
    // defer-rescale: exact (om stays the true running row max)
    if (__any(cm > om)) {
      float nm = fmaxf(om, cm);
      float sc = __expf(om - nm);  // 0 on first chunk
      om = nm;
      float scr[4];
#pragma unroll
      for (int rg = 0; rg < 4; ++rg) scr[rg] = __shfl(sc, 4 * lg + rg);
#pragma unroll
      for (int rg = 0; rg < 4; ++rg) dacc[rg] *= scr[rg];
#pragma unroll
      for (int db = 0; db < 8; ++db)
#pragma unroll
        for (int rg = 0; rg < 4; ++rg) cacc[db][rg] *= scr[rg];
    }
    float dqm = dq + om;
    float ev[8];
#pragma unroll
    for (int ms = 0; ms < 2; ++ms)
#pragma unroll
      for (int rg = 0; rg < 4; ++rg)
        ev[ms * 4 + rg] = __expf(qk[ms][rg] - dqm);
    union { short8 s8; unsigned u[4]; } ea;
#pragma unroll
    for (int i = 0; i < 4; ++i) ea.u[i] = cvtpk(ev[2 * i], ev[2 * i + 1]);
    __builtin_amdgcn_s_setprio(1);
    // den via MFMA: B-fragment = pi-permuted bf16 ksum slice (broadcast read)
    dacc = __builtin_amdgcn_mfma_f32_16x16x32_bf16(
        ea.s8, *(const short8*)&kslp[m0 + lg * 8], dacc, 0, 0, 0);
#pragma unroll
    for (int db = 0; db < 8; ++db)
      cacc[db] = __builtin_amdgcn_mfma_f32_16x16x32_bf16(
          ea.s8, *(const short8*)(Ct[cur] + (db * 16 + lr) * 64 + ((lg * 16) ^ xv)),
          cacc[db], 0, 0, 0);
    __builtin_amdgcn_s_setprio(0);
    __syncthreads();
  }
  float kst = ksumtot[bh];
  float dinv[4];
#pragma unroll
  for (int rg = 0; rg < 4; ++rg)
    dinv[rg] = 1.f / (RATIO_ * (dacc[rg] + EPS_ * kst));
  short* ob = o + ((size_t)bh * N_ + nt * 128 + w * 16) * DH_;
#pragma unroll
  for (int db = 0; db < 8; ++db) {
    int d = db * 16 + lr;
    float cs = ctxsum[bh * DH_ + d] * EPS_;
#pragma unroll
    for (int rg = 0; rg < 4; ++rg)
      ob[(size_t)(4 * lg + rg) * DH_ + d] =
          f2bf(RATIO_ * (cacc[db][rg] + cs) * dinv[rg]);
  }
}

// ----- Wo projection (wave-per-token, bf16 in) + residual + LN2 + FFN +
// residual, fused: lanes 0..7 finish one token each. grid B*N/32, 256 thr.
__global__ __launch_bounds__(256) void k_wo_ffn(
    const short* __restrict__ attn, const float* __restrict__ Wo,
    const float* __restrict__ bo, const float* __restrict__ g2,
    const float* __restrict__ be2, const float* __restrict__ W1,
    const float* __restrict__ bf1, const float* __restrict__ W2,
    const float* __restrict__ bf2, float* __restrict__ x) {
  __shared__ float wols[INNER_ * 3];
  __shared__ float bos[3];
  __shared__ float acc3[4][8][3];
  int t = threadIdx.x;
  for (int i = t; i < INNER_ * 3; i += 256) wols[i] = Wo[i];
  if (t < 3) bos[t] = bo[t];
  __syncthreads();
  int w = t >> 6, l = t & 63;
  int base = (blockIdx.x * 4 + w) * 8;
#pragma unroll
  for (int tt = 0; tt < 8; ++tt) {
    int token = base + tt;
    int b = token >> 12, n = token & 4095;
    float p0 = 0.f, p1 = 0.f, p2 = 0.f;
#pragma unroll
    for (int s = 0; s < 6; ++s) {
      int inner = l + 64 * s;
      int h = inner >> 7, dh = inner & 127;
      float a = bf2f(attn[(((size_t)(b * H_ + h)) * N_ + n) * DH_ + dh]);
      p0 = fmaf(a, wols[inner * 3 + 0], p0);
      p1 = fmaf(a, wols[inner * 3 + 1], p1);
      p2 = fmaf(a, wols[inner * 3 + 2], p2);
    }
#pragma unroll
    for (int off = 32; off; off >>= 1) {
      p0 += __shfl_down(p0, off);
      p1 += __shfl_down(p1, off);
      p2 += __shfl_down(p2, off);
    }
    if (l == 0) {
      acc3[w][tt][0] = p0 + bos[0];
      acc3[w][tt][1] = p1 + bos[1];
      acc3[w][tt][2] = p2 + bos[2];
    }
  }
  __syncthreads();
  if (l < 8) {
    int token = base + l;
    float x0 = x[(size_t)token * 3 + 0] + acc3[w][l][0];
    float x1 = x[(size_t)token * 3 + 1] + acc3[w][l][1];
    float x2 = x[(size_t)token * 3 + 2] + acc3[w][l][2];
    float mu = (x0 + x1 + x2) * (1.f / 3.f);
    float d0 = x0 - mu, d1 = x1 - mu, d2 = x2 - mu;
    float rs = rsqrtf((d0 * d0 + d1 * d1 + d2 * d2) * (1.f / 3.f) + 1e-5f);
    float h0 = d0 * rs * g2[0] + be2[0];
    float h1 = d1 * rs * g2[1] + be2[1];
    float h2 = d2 * rs * g2[2] + be2[2];
    float y0 = x0 + bf2[0], y1 = x1 + bf2[1], y2 = x2 + bf2[2];
#pragma unroll
    for (int tt = 0; tt < 12; ++tt) {
      float f = h0 * W1[tt] + h1 * W1[12 + tt] + h2 * W1[24 + tt] + bf1[tt];
      float g = 0.5f * f * (1.f + erff(f * 0.70710678118654752f));
      y0 += g * W2[tt * 3 + 0];
      y1 += g * W2[tt * 3 + 1];
      y2 += g * W2[tt * 3 + 2];
    }
    x[(size_t)token * 3 + 0] = y0;
    x[(size_t)token * 3 + 1] = y1;
    x[(size_t)token * 3 + 2] = y2;
  }
}

// ---------------------------------------------------------- decoder
__global__ void k_decode(const float* __restrict__ x, const float* __restrict__ dw,
                         const float* __restrict__ db, float* __restrict__ out) {
  int t = blockIdx.x * 256 + threadIdx.x;
  if (t < B_ * N_) {
    float l = x[(size_t)t * 3 + 0] * dw[0] + x[(size_t)t * 3 + 1] * dw[1] +
              x[(size_t)t * 3 + 2] * dw[2] + db[0];
    out[t] = 1.f / (1.f + expf(-l));
  }
}

// ================================================================ launch
extern "C" void kernel_launch(void* const* d_in, const int* in_sizes, int n_in,
                              void* d_out, int out_size, void* d_ws, size_t ws_size,
                              hipStream_t stream) {
  const float* x_in = (const float*)d_in[0];
  const float* Wq = (const float*)d_in[1];
  const float* Wk = (const float*)d_in[2];
  const float* Wv = (const float*)d_in[3];
  const float* Wo = (const float*)d_in[4];
  const float* bo = (const float*)d_in[5];
  const float* ln1g = (const float*)d_in[6];
  const float* ln1b = (const float*)d_in[7];
  const float* W1 = (const float*)d_in[8];
  const float* b1 = (const float*)d_in[9];
  const float* W2 = (const float*)d_in[10];
  const float* b2 = (const float*)d_in[11];
  const float* ln2g = (const float*)d_in[12];
  const float* ln2b = (const float*)d_in[13];
  const float* proj = (const float*)d_in[14];
  const float* dec_w = (const float*)d_in[15];
  const float* dec_b = (const float*)d_in[16];

  const size_t XB = (size_t)B_ * N_ * 3;
  const size_t QKV = (size_t)BH_ * N_ * DH_;       // 12582912
  const size_t CTX = (size_t)BH_ * MP_ * DH_;      // 1966080
  const size_t SS = (size_t)BH_ * MP_;

  char* p = (char*)d_ws;
  auto alloc = [&](size_t bytes) {
    char* r = p;
    p += (bytes + 255) & ~(size_t)255;
    return r;
  };
  float* xbuf = (float*)alloc(XB * 4);
  short* qb = (short*)alloc(QKV * 2);
  short* kb = (short*)alloc(QKV * 2);
  float* diag_k = (float*)alloc((size_t)BH_ * N_ * 4);
  short* pb = (short*)alloc((size_t)DEPTH_ * MP_ * DH_ * 2);
  short* vtp = (short*)alloc(QKV * 2);
  short* ctxtp = (short*)alloc(CTX * 2);
  // Cpart (31.5MB fp32) and o (25MB bf16) have disjoint lifetimes -> alias
  float* Cpart = (float*)alloc((size_t)4 * BH_ * MP_ * DH_ * 4);
  short* o = (short*)Cpart;
  float* spart = (float*)alloc(4 * SS * 4);
  float* cspart = (float*)alloc((size_t)BH_ * 20 * DH_ * 4);
  short* ksum_pb = (short*)alloc(SS * 2);
  float* vsppart = (float*)alloc((size_t)BH_ * DH_ * 128 * 4);
  float* ctxsum = (float*)alloc((size_t)BH_ * DH_ * 4);
  float* ksumtot = (float*)alloc(BH_ * 4);
  float* bmx = (float*)alloc((size_t)4 * BH_ * 40 * 4);

  k_copy<<<(XB + 255) / 256, 256, 0, stream>>>(x_in, xbuf, (int)XB);
  k_projcvt<<<(DEPTH_ * MP_ * DH_ + 255) / 256, 256, 0, stream>>>(proj, pb);

  for (int i = 0; i < DEPTH_; ++i) {
    const short* pbL = pb + (size_t)i * MP_ * DH_;
    k_ln_qkv<<<B_ * N_ / 32, 384, 0, stream>>>(xbuf, Wq + (size_t)i * 3 * INNER_,
                                               Wk + (size_t)i * 3 * INNER_,
                                               Wv + (size_t)i * 3 * INNER_,
                                               ln1g + i * 3, ln1b + i * 3,
                                               qb, kb, vtp, diag_k, vsppart);
    k_kp_ctx<<<dim3(4, 5, BH_), 512, 0, stream>>>(kb, vtp, pbL, diag_k,
                                                  Cpart, spart, bmx);
    k_fin_ctx<<<dim3(20, BH_), 256, 0, stream>>>(Cpart, vsppart, bmx, ctxtp, cspart);
    k_fin2<<<BH_, 128, 0, stream>>>(cspart, spart, bmx, ctxsum, ksum_pb, ksumtot);
    k_q_attn<<<dim3(32, BH_), 512, 0, stream>>>(qb, pbL, ctxtp, ksum_pb,
                                                ctxsum, ksumtot, o);
    k_wo_ffn<<<B_ * N_ / 32, 256, 0, stream>>>(o, Wo + (size_t)i * INNER_ * 3,
                                               bo + i * 3, ln2g + i * 3, ln2b + i * 3,
                                               W1 + (size_t)i * 36, b1 + (size_t)i * 12,
                                               W2 + (size_t)i * 36, b2 + i * 3, xbuf);
  }
  k_decode<<<(B_ * N_ + 255) / 256, 256, 0, stream>>>(xbuf, dec_w, dec_b, (float*)d_out);
}

// Round 18
// 1033.488 us; speedup vs baseline: 1.1183x; 1.1183x over previous
//
#include <hip/hip_runtime.h>
#include <math.h>

// Performer (FAVOR+) forward, 6 layers. bf16 MFMA + global_load_lds staging.
// Round 18: round-15 structure restored (separate k_dv; fusion reverted);
// keeps the proven bf16-o change (q_attn stores bf16, wo_ffn reads bf16).
// B=8 N=4096 DIM=3 H=3 DH=128 INNER=384 M=620(pad 640) FF=12
#define B_ 8
#define N_ 4096
#define H_ 3
#define DH_ 128
#define INNER_ 384
#define M_ 620
#define MP_ 640
#define DEPTH_ 6
#define BH_ 24

static constexpr float DN_ = 0.29730177875068026f;     // 128^-0.25
static constexpr float RATIO_ = 0.04016096644512494f;  // 620^-0.5
static constexpr float EPS_ = 1e-4f;

typedef __attribute__((ext_vector_type(8))) short short8;
typedef __attribute__((ext_vector_type(4))) float f32x4;

__device__ __forceinline__ short f2bf(float f) {
  union { float f; unsigned u; } x; x.f = f;
  unsigned r = x.u + 0x7FFF + ((x.u >> 16) & 1);
  return (short)(r >> 16);
}
__device__ __forceinline__ float bf2f(short s) {
  union { unsigned u; float f; } x; x.u = ((unsigned)(unsigned short)s) << 16;
  return x.f;
}
__device__ __forceinline__ float4 ldg4(const float* p) { return *(const float4*)p; }

// packed f32x2 -> bf16x2 (RNE), one VALU op
__device__ __forceinline__ unsigned cvtpk(float lo, float hi) {
  unsigned r;
  asm("v_cvt_pk_bf16_f32 %0, %1, %2" : "=v"(r) : "v"(lo), "v"(hi));
  return r;
}

// async global->LDS DMA, 16B per lane. LDS dest = uniform base + lane*16.
__device__ __forceinline__ void gl2lds(const void* g, void* l) {
  __builtin_amdgcn_global_load_lds(
      (const __attribute__((address_space(1))) void*)g,
      (__attribute__((address_space(3))) void*)l, 16, 0, 0);
}

// stage a 32-row x 256B tile, 8 waves (one DMA/lane). read back with:
// ofs = row*256 + (want ^ ((row&7)<<4))
__device__ __forceinline__ void stage_t256(const char* gbase, char* lds, int w, int l) {
  int row = w * 4 + (l >> 4);
  int col = ((l & 15) * 16) ^ ((row & 7) << 4);
  char* lp = lds + __builtin_amdgcn_readfirstlane(w << 10);
  gl2lds(gbase + row * 256 + col, lp);
}

// stage a 128-row x 64B tile (row stride growb bytes), 8 waves, swizzle
// sw64(d) = ((d ^ (d>>2)) & 3) << 4. read back: ofs = d*64 + (want ^ sw64(d))
__device__ __forceinline__ void stage_t64(const char* gbase, size_t growb, char* lds,
                                          int w, int l) {
  int d = w * 16 + (l >> 2);
  int swl = ((((l >> 2) ^ (l >> 4)) & 3) << 4);  // == sw64(d) for this lane
  int col = ((l & 3) * 16) ^ swl;
  char* lp = lds + __builtin_amdgcn_readfirstlane(w << 10);
  gl2lds(gbase + (size_t)d * growb + col, lp);
}

// ---------------------------------------------------------------- copy
__global__ void k_copy(const float* __restrict__ s, float* __restrict__ d, int n) {
  int i = blockIdx.x * 256 + threadIdx.x;
  if (i < n) d[i] = s[i];
}

// ------------------------------------------- proj -> bf16, padded to 640 rows
__global__ void k_projcvt(const float* __restrict__ proj, short* __restrict__ pb) {
  int i = blockIdx.x * 256 + threadIdx.x;
  if (i >= DEPTH_ * MP_ * DH_) return;
  int l = i / (MP_ * DH_);
  int rem = i - l * (MP_ * DH_);
  int m = rem >> 7, d = rem & 127;
  pb[i] = (m < M_) ? f2bf(proj[((size_t)l * M_ + m) * DH_ + d]) : (short)0;
}

// ---------- LN1 + QKV; 32 tokens/block; emits q,k row-major AND v directly
// transposed+pi-permuted into vtp (thread owns full n-row in registers).
__global__ __launch_bounds__(384) void k_ln_qkv(
    const float* __restrict__ x, const float* __restrict__ Wq,
    const float* __restrict__ Wk, const float* __restrict__ Wv,
    const float* __restrict__ g1, const float* __restrict__ b1,
    short* __restrict__ qb, short* __restrict__ kb, short* __restrict__ vtp) {
  __shared__ float xs[96];
  int c = threadIdx.x;
  int token0 = blockIdx.x * 32;
  int b = token0 >> 12, n0 = token0 & 4095;
  if (c < 96) xs[c] = x[(size_t)token0 * 3 + c];
  float wq0 = Wq[c], wq1 = Wq[INNER_ + c], wq2 = Wq[2 * INNER_ + c];
  float wk0 = Wk[c], wk1 = Wk[INNER_ + c], wk2 = Wk[2 * INNER_ + c];
  float wv0 = Wv[c], wv1 = Wv[INNER_ + c], wv2 = Wv[2 * INNER_ + c];
  float G0 = g1[0], G1 = g1[1], G2 = g1[2];
  float B0 = b1[0], B1 = b1[1], B2 = b1[2];
  int hh = c >> 7, dh = c & 127;
  size_t rowbase = ((size_t)(b * H_ + hh) * N_ + n0) * DH_ + dh;
  __syncthreads();
  short8 v8[4];
#pragma unroll
  for (int tt = 0; tt < 32; ++tt) {
    float x0 = xs[tt * 3], x1 = xs[tt * 3 + 1], x2 = xs[tt * 3 + 2];
    float mu = (x0 + x1 + x2) * (1.f / 3.f);
    float d0 = x0 - mu, d1 = x1 - mu, d2 = x2 - mu;
    float rs = rsqrtf((d0 * d0 + d1 * d1 + d2 * d2) * (1.f / 3.f) + 1e-5f);
    float h0 = d0 * rs * G0 + B0;
    float h1 = d1 * rs * G1 + B1;
    float h2 = d2 * rs * G2 + B2;
    qb[rowbase + (size_t)tt * DH_] = f2bf((h0 * wq0 + h1 * wq1 + h2 * wq2) * DN_);
    kb[rowbase + (size_t)tt * DH_] = f2bf((h0 * wk0 + h1 * wk1 + h2 * wk2) * DN_);
    const int p = ((tt >> 2) & 3) * 8 + ((tt >> 4) & 1) * 4 + (tt & 3);
    v8[p >> 3][p & 7] = f2bf(h0 * wv0 + h1 * wv1 + h2 * wv2);
  }
  short* dst = vtp + ((size_t)(b * H_ + hh) * DH_ + dh) * N_ + n0;
  *(short8*)dst = v8[0];
  *(short8*)(dst + 8) = v8[1];
  *(short8*)(dst + 16) = v8[2];
  *(short8*)(dst + 24) = v8[3];
}

// ---------- merged diag_k + vsum. grid (256, 24): x<128 -> vsum col d=x,
// x>=128 -> diag for n-tile x-128. 256 threads.
__global__ __launch_bounds__(256) void k_dv(
    const short* __restrict__ kb, const short* __restrict__ vtp,
    float* __restrict__ diag_k, float* __restrict__ vsp) {
  __shared__ float red[256];
  int xx = blockIdx.x, bh = blockIdx.y, t = threadIdx.x;
  if (xx < 128) {
    int d = xx;
    const short8* row = (const short8*)(vtp + ((size_t)bh * DH_ + d) * N_);
    short8 a = row[t * 2], b2 = row[t * 2 + 1];
    float s = 0.f;
#pragma unroll
    for (int j = 0; j < 8; ++j) s += bf2f(a[j]) + bf2f(b2[j]);
    red[t] = s;
    __syncthreads();
    for (int st = 128; st; st >>= 1) {
      if (t < st) red[t] += red[t + st];
      __syncthreads();
    }
    if (t == 0) vsp[bh * DH_ + d] = red[0];
  } else {
    int nt = xx - 128;
    int n = t >> 3, seg = t & 7;
    const short* src = kb + ((size_t)bh * N_ + nt * 32 + n) * DH_ + seg * 16;
    short8 a = *(const short8*)src;
    short8 b2 = *(const short8*)(src + 8);
    float s = 0.f;
#pragma unroll
    for (int j = 0; j < 8; ++j) {
      float va = bf2f(a[j]), vb = bf2f(b2[j]);
      s = fmaf(va, va, s);
      s = fmaf(vb, vb, s);
    }
    s += __shfl_down(s, 4);
    s += __shfl_down(s, 2);
    s += __shfl_down(s, 1);
    if (seg == 0) diag_k[(size_t)bh * N_ + nt * 32 + n] = 0.5f * s;
  }
}

// ------------- key features -> ctx partials (K,Vt via LDS double-buffer,
// PAIR-CHUNKED: 2 n-chunks per barrier period, 16 barriers total).
// grid (4 ns, 5 mt, 24 bh), 512 threads. Per-wave ONLINE max (exact).
__global__ __launch_bounds__(512) void k_kp_ctx(
    const short* __restrict__ kb, const short* __restrict__ vtp,
    const short* __restrict__ pb, const float* __restrict__ diag_k,
    float* __restrict__ Cpart, float* __restrict__ spart,
    float* __restrict__ bmx) {
  int ns = blockIdx.x, mt = blockIdx.y, bh = blockIdx.z;
  __shared__ __align__(16) char Ks[2][16384];
  __shared__ __align__(16) char Vts[2][16384];
  __shared__ float diag_s[1024];
  int t = threadIdx.x, w = t >> 6, l = t & 63, lr = l & 15, lg = l >> 4;
  {
    const float* dbase = diag_k + (size_t)bh * N_ + ns * 1024;
#pragma unroll
    for (int i = 0; i < 2; ++i) diag_s[t + i * 512] = dbase[t + i * 512];
  }
  int m0 = mt * 128 + w * 16;
  short8 bfr[4];
  {
    const short* pr = pb + (size_t)(m0 + lr) * DH_ + lg * 8;
#pragma unroll
    for (int ks = 0; ks < 4; ++ks) bfr[ks] = *(const short8*)(pr + ks * 32);
  }
  const char* kgb = (const char*)(kb + ((size_t)bh * N_ + ns * 1024) * DH_);
  const char* vgb = (const char*)(vtp + (size_t)bh * DH_ * N_ + ns * 1024);
  stage_t256(kgb, Ks[0], w, l);
  stage_t256(kgb + 32 * 256, Ks[0] + 8192, w, l);
  stage_t64(vgb, (size_t)N_ * 2, Vts[0], w, l);
  stage_t64(vgb + 64, (size_t)N_ * 2, Vts[0] + 8192, w, l);
  __syncthreads();
  f32x4 cacc[8];
#pragma unroll
  for (int db = 0; db < 8; ++db) cacc[db] = (f32x4){0.f, 0.f, 0.f, 0.f};
  float ksacc = 0.f;
  float bm = -INFINITY;  // wave-uniform running max of valid dd
  const bool mv = (m0 + lr) < M_;
  int xk = (lr & 7) << 4;
  int xv = ((lr ^ (lr >> 2)) & 3) << 4;  // sw64(db*16+lr), db-independent
  for (int pc = 0; pc < 16; ++pc) {
    int cur = pc & 1;
    if (pc < 15) {
      const char* kc = kgb + (size_t)(2 * pc + 2) * 32 * 256;
      stage_t256(kc, Ks[cur ^ 1], w, l);
      stage_t256(kc + 32 * 256, Ks[cur ^ 1] + 8192, w, l);
      const char* vc = vgb + (size_t)(2 * pc + 2) * 64;
      stage_t64(vc, (size_t)N_ * 2, Vts[cur ^ 1], w, l);
      stage_t64(vc + 64, (size_t)N_ * 2, Vts[cur ^ 1] + 8192, w, l);
    }
#pragma unroll
    for (int sub = 0; sub < 2; ++sub) {
      const char* KS = Ks[cur] + sub * 8192;
      const char* VS = Vts[cur] + sub * 8192;
      int n0 = (2 * pc + sub) * 32;
      f32x4 dd[2];
      __builtin_amdgcn_s_setprio(1);
#pragma unroll
      for (int nsub = 0; nsub < 2; ++nsub) {
        f32x4 acc = {0.f, 0.f, 0.f, 0.f};
#pragma unroll
        for (int ks = 0; ks < 4; ++ks)
          acc = __builtin_amdgcn_mfma_f32_16x16x32_bf16(
              *(const short8*)(KS + (nsub * 16 + lr) * 256 +
                               ((lg * 16 + ks * 64) ^ xk)),
              bfr[ks], acc, 0, 0, 0);
        dd[nsub] = acc;
      }
      __builtin_amdgcn_s_setprio(0);
      // wave-uniform online max over valid m (6-step xor reduce)
      float cm = -INFINITY;
      if (mv) {
#pragma unroll
        for (int nsub = 0; nsub < 2; ++nsub)
#pragma unroll
          for (int rg = 0; rg < 4; ++rg) cm = fmaxf(cm, dd[nsub][rg]);
      }
#pragma unroll
      for (int off = 1; off < 64; off <<= 1) cm = fmaxf(cm, __shfl_xor(cm, off));
      if (cm > bm) {  // wave-uniform
        float sc = __expf(bm - cm);  // 0 on first trigger
        bm = cm;
        ksacc *= sc;
#pragma unroll
        for (int db = 0; db < 8; ++db)
#pragma unroll
          for (int rg = 0; rg < 4; ++rg) cacc[db][rg] *= sc;
      }
      float ev[8];
#pragma unroll
      for (int nsub = 0; nsub < 2; ++nsub)
#pragma unroll
        for (int rg = 0; rg < 4; ++rg) {
          float e = __expf(dd[nsub][rg] - diag_s[n0 + nsub * 16 + 4 * lg + rg] - bm);
          ev[nsub * 4 + rg] = e;
          ksacc += e;
        }
      union { short8 s8; unsigned u[4]; } ea;
#pragma unroll
      for (int i = 0; i < 4; ++i) ea.u[i] = cvtpk(ev[2 * i], ev[2 * i + 1]);
      __builtin_amdgcn_s_setprio(1);
#pragma unroll
      for (int db = 0; db < 8; ++db)
        cacc[db] = __builtin_amdgcn_mfma_f32_16x16x32_bf16(
            ea.s8, *(const short8*)(VS + (db * 16 + lr) * 64 + ((lg * 16) ^ xv)),
            cacc[db], 0, 0, 0);
      __builtin_amdgcn_s_setprio(0);
    }
    __syncthreads();
  }
  float* Cp = Cpart + ((size_t)ns * BH_ + bh) * MP_ * DH_;
#pragma unroll
  for (int db = 0; db < 8; ++db) {
    int d = db * 16 + lr;
#pragma unroll
    for (int rg = 0; rg < 4; ++rg)
      Cp[(size_t)(m0 + 4 * lg + rg) * DH_ + d] = cacc[db][rg];
  }
  ksacc += __shfl_down(ksacc, 32);
  ksacc += __shfl_down(ksacc, 16);
  if (l < 16) spart[((size_t)ns * BH_ + bh) * MP_ + m0 + l] = ksacc;
  if (l == 0) bmx[((size_t)ns * BH_ + bh) * 40 + mt * 8 + w] = bm;
}

// ------ finalize ctx: weighted merge of 4 ns partials (exp(bm-mx)) + EPS*vsum,
// emit pi-permuted bf16 ctxtp tile + colsum partial. mx reduced inline.
// grid (20 mt, 24 bh), 256 threads.
__global__ __launch_bounds__(256) void k_fin_ctx(
    const float* __restrict__ Cpart, const float* __restrict__ vsp,
    const float* __restrict__ bmx,
    short* __restrict__ ctxtp, float* __restrict__ cspart) {
  int mt = blockIdx.x, bh = blockIdx.y;
  __shared__ float vsv[128];
  __shared__ short tile[128][40];
  __shared__ float redm[4];
  int t = threadIdx.x;
  if (t < 128) vsv[t] = vsp[bh * DH_ + t] * EPS_;
  float v = -INFINITY;
  if (t < 160) {
    int nsg = t / 40, g = t - nsg * 40;
    v = bmx[((size_t)nsg * BH_ + bh) * 40 + g];
  }
#pragma unroll
  for (int off = 32; off; off >>= 1) v = fmaxf(v, __shfl_xor(v, off));
  if ((t & 63) == 0) redm[t >> 6] = v;
  __syncthreads();
  float mxg = fmaxf(fmaxf(redm[0], redm[1]), fmaxf(redm[2], redm[3]));
  int r = t >> 3, seg = t & 7;
  int d0 = seg * 16;
  int m = mt * 32 + r;
  int p = ((r >> 2) & 3) * 8 + ((r >> 4) & 1) * 4 + (r & 3);
  const size_t ph = (size_t)BH_ * MP_ * DH_;
  const float* c0 = Cpart + (size_t)bh * MP_ * DH_ + (size_t)m * DH_ + d0;
  if (m < M_) {
    int g = m >> 4;
    float sc0 = __expf(bmx[((size_t)0 * BH_ + bh) * 40 + g] - mxg);
    float sc1 = __expf(bmx[((size_t)1 * BH_ + bh) * 40 + g] - mxg);
    float sc2 = __expf(bmx[((size_t)2 * BH_ + bh) * 40 + g] - mxg);
    float sc3 = __expf(bmx[((size_t)3 * BH_ + bh) * 40 + g] - mxg);
#pragma unroll
    for (int j4 = 0; j4 < 4; ++j4) {
      float4 a = ldg4(c0 + j4 * 4);
      float4 b = ldg4(c0 + ph + j4 * 4);
      float4 c = ldg4(c0 + 2 * ph + j4 * 4);
      float4 e = ldg4(c0 + 3 * ph + j4 * 4);
      float vals[4] = {sc0 * a.x + sc1 * b.x + sc2 * c.x + sc3 * e.x,
                       sc0 * a.y + sc1 * b.y + sc2 * c.y + sc3 * e.y,
                       sc0 * a.z + sc1 * b.z + sc2 * c.z + sc3 * e.z,
                       sc0 * a.w + sc1 * b.w + sc2 * c.w + sc3 * e.w};
#pragma unroll
      for (int j = 0; j < 4; ++j) {
        int d = d0 + j4 * 4 + j;
        tile[d][p] = f2bf(RATIO_ * (vals[j] + vsv[d]));
      }
    }
  } else {
#pragma unroll
    for (int j = 0; j < 16; ++j) tile[d0 + j][p] = 0;
  }
  __syncthreads();
  int d = t >> 1, half = t & 1;
  short* dst = ctxtp + ((size_t)bh * DH_ + d) * MP_ + mt * 32 + half * 16;
  short8 s0 = *(const short8*)&tile[d][half * 16];
  short8 s1 = *(const short8*)&tile[d][half * 16 + 8];
  *(short8*)dst = s0;
  *(short8*)(dst + 8) = s1;
  float cs = 0.f;
#pragma unroll
  for (int j = 0; j < 8; ++j) cs += bf2f(s0[j]) + bf2f(s1[j]);
  cs += __shfl_xor(cs, 1);
  if (half == 0) cspart[((size_t)bh * 20 + mt) * DH_ + d] = cs;
}

// ------ small finalize: ctxsum, weighted ksum merge (mx inline), ksum_pb
__global__ __launch_bounds__(128) void k_fin2(
    const float* __restrict__ cspart, const float* __restrict__ spart,
    const float* __restrict__ bmx,
    float* __restrict__ ctxsum, short* __restrict__ ksum_pb,
    float* __restrict__ ksumtot) {
  int bh = blockIdx.x, d = threadIdx.x;
  __shared__ float redm[2];
  float v = -INFINITY;
  for (int i = d; i < 160; i += 128) {
    int nsg = i / 40, g = i - nsg * 40;
    v = fmaxf(v, bmx[((size_t)nsg * BH_ + bh) * 40 + g]);
  }
#pragma unroll
  for (int off = 32; off; off >>= 1) v = fmaxf(v, __shfl_xor(v, off));
  if ((d & 63) == 0) redm[d >> 6] = v;
  float s = 0.f;
#pragma unroll
  for (int mt = 0; mt < 20; ++mt) s += cspart[((size_t)bh * 20 + mt) * DH_ + d];
  ctxsum[bh * DH_ + d] = s;
  __syncthreads();
  float mxg = fmaxf(redm[0], redm[1]);
  __shared__ float red[128];
  float kt = 0.f;
  for (int m = d; m < MP_; m += 128) {
    float ks = 0.f;
    if (m < M_) {
      size_t o = (size_t)bh * MP_ + m;
      size_t sh = (size_t)BH_ * MP_;
      int g = m >> 4;
      float s0 = __expf(bmx[((size_t)0 * BH_ + bh) * 40 + g] - mxg);
      float s1 = __expf(bmx[((size_t)1 * BH_ + bh) * 40 + g] - mxg);
      float s2 = __expf(bmx[((size_t)2 * BH_ + bh) * 40 + g] - mxg);
      float s3 = __expf(bmx[((size_t)3 * BH_ + bh) * 40 + g] - mxg);
      ks = RATIO_ * (s0 * spart[o] + s1 * spart[o + sh] + s2 * spart[o + 2 * sh] +
                     s3 * spart[o + 3 * sh] + EPS_ * (float)N_);
    }
    int r = m & 31;
    int p = ((r >> 2) & 3) * 8 + ((r >> 4) & 1) * 4 + (r & 3);
    ksum_pb[(size_t)bh * MP_ + (m & ~31) + p] = f2bf(ks);
    kt += ks;
  }
  red[d] = kt;
  __syncthreads();
  for (int st = 64; st > 0; st >>= 1) {
    if (d < st) red[d] += red[d + st];
    __syncthreads();
  }
  if (d == 0) ksumtot[bh] = red[0];
}

// -------- query side: online softmax (defer-rescale), den via MFMA,
// cvt_pk packing, bf16 output. grid (32 nt, 24 bh), 512 threads.
__global__ __launch_bounds__(512) void k_q_attn(
    const short* __restrict__ qb, const short* __restrict__ pb,
    const short* __restrict__ ctxtp, const short* __restrict__ ksum_pb,
    const float* __restrict__ ctxsum, const float* __restrict__ ksumtot,
    short* __restrict__ o) {
  int nt = blockIdx.x, bh = blockIdx.y;
  __shared__ __align__(16) char Pj[2][8192];
  __shared__ __align__(16) char Ct[2][8192];
  __shared__ __align__(16) short kslp[MP_];
  int t = threadIdx.x, w = t >> 6, l = t & 63, lr = l & 15, lg = l >> 4;
  if (t < MP_ / 8)
    ((short8*)kslp)[t] = ((const short8*)(ksum_pb + (size_t)bh * MP_))[t];
  const short* qr = qb + ((size_t)bh * N_ + nt * 128 + w * 16 + lr) * DH_ + lg * 8;
  short8 qfr[4];
#pragma unroll
  for (int ks = 0; ks < 4; ++ks) qfr[ks] = *(const short8*)(qr + ks * 32);
  // diag_q from fragments (bf16-consistent)
  float dq;
  {
    float s2 = 0.f;
#pragma unroll
    for (int ks = 0; ks < 4; ++ks)
#pragma unroll
      for (int j = 0; j < 8; ++j) {
        float v = bf2f(qfr[ks][j]);
        s2 = fmaf(v, v, s2);
      }
    s2 += __shfl_xor(s2, 16);
    s2 += __shfl_xor(s2, 32);
    dq = 0.5f * s2;
  }
  const char* cgb = (const char*)(ctxtp + (size_t)bh * DH_ * MP_);
  stage_t256((const char*)pb, Pj[0], w, l);
  stage_t64(cgb, (size_t)MP_ * 2, Ct[0], w, l);
  __syncthreads();
  f32x4 cacc[8];
#pragma unroll
  for (int db = 0; db < 8; ++db) cacc[db] = (f32x4){0.f, 0.f, 0.f, 0.f};
  f32x4 dacc = {0.f, 0.f, 0.f, 0.f};
  float om = -INFINITY;
  int xk = (lr & 7) << 4;
  int xv = ((lr ^ (lr >> 2)) & 3) << 4;  // sw64(db*16+lr), db-independent
  for (int mc = 0; mc < 20; ++mc) {
    int cur = mc & 1;
    if (mc < 19) {
      stage_t256((const char*)(pb + (size_t)(mc + 1) * 32 * DH_), Pj[cur ^ 1], w, l);
      stage_t64(cgb + (size_t)(mc + 1) * 64, (size_t)MP_ * 2, Ct[cur ^ 1], w, l);
    }
    int m0 = mc * 32;
    f32x4 qk[2];
    __builtin_amdgcn_s_setprio(1);
#pragma unroll
    for (int ms = 0; ms < 2; ++ms) {
      f32x4 acc = {0.f, 0.f, 0.f, 0.f};
#pragma unroll
      for (int ks = 0; ks < 4; ++ks)
        acc = __builtin_amdgcn_mfma_f32_16x16x32_bf16(
            *(const short8*)(Pj[cur] + (ms * 16 + lr) * 256 +
                             ((lg * 16 + ks * 64) ^ xk)),
            qfr[ks], acc, 0, 0, 0);
      qk[ms] = acc;
    }
    __builtin_amdgcn_s_setprio(0);
    // chunk row-max (rows n = lr; reduce across lg lane groups)
    float cm = -INFINITY;
#pragma unroll
    for (int ms = 0; ms < 2; ++ms)
#pragma unroll
      for (int rg = 0; rg < 4; ++rg) {
        int mg = m0 + ms * 16 + 4 * lg + rg;
        if (mg < M_) cm = fmaxf(cm, qk[ms][rg]);
      }
    cm = fmaxf(cm, __shfl_xor(cm, 16));
    cm = fmaxf(cm, __shfl_xor(cm, 32));
    // defer-rescale: exact (om stays the true running row max)
    if (__any(cm > om)) {
      float nm = fmaxf(om, cm);
      float sc = __expf(om - nm);  // 0 on first chunk
      om = nm;
      float scr[4];
#pragma unroll
      for (int rg = 0; rg < 4; ++rg) scr[rg] = __shfl(sc, 4 * lg + rg);
#pragma unroll
      for (int rg = 0; rg < 4; ++rg) dacc[rg] *= scr[rg];
#pragma unroll
      for (int db = 0; db < 8; ++db)
#pragma unroll
        for (int rg = 0; rg < 4; ++rg) cacc[db][rg] *= scr[rg];
    }
    float dqm = dq + om;
    float ev[8];
#pragma unroll
    for (int ms = 0; ms < 2; ++ms)
#pragma unroll
      for (int rg = 0; rg < 4; ++rg)
        ev[ms * 4 + rg] = __expf(qk[ms][rg] - dqm);
    union { short8 s8; unsigned u[4]; } ea;
#pragma unroll
    for (int i = 0; i < 4; ++i) ea.u[i] = cvtpk(ev[2 * i], ev[2 * i + 1]);
    __builtin_amdgcn_s_setprio(1);
    // den via MFMA: B-fragment = pi-permuted bf16 ksum slice (broadcast read)
    dacc = __builtin_amdgcn_mfma_f32_16x16x32_bf16(
        ea.s8, *(const short8*)&kslp[m0 + lg * 8], dacc, 0, 0, 0);
#pragma unroll
    for (int db = 0; db < 8; ++db)
      cacc[db] = __builtin_amdgcn_mfma_f32_16x16x32_bf16(
          ea.s8, *(const short8*)(Ct[cur] + (db * 16 + lr) * 64 + ((lg * 16) ^ xv)),
          cacc[db], 0, 0, 0);
    __builtin_amdgcn_s_setprio(0);
    __syncthreads();
  }
  float kst = ksumtot[bh];
  float dinv[4];
#pragma unroll
  for (int rg = 0; rg < 4; ++rg)
    dinv[rg] = 1.f / (RATIO_ * (dacc[rg] + EPS_ * kst));
  short* ob = o + ((size_t)bh * N_ + nt * 128 + w * 16) * DH_;
#pragma unroll
  for (int db = 0; db < 8; ++db) {
    int d = db * 16 + lr;
    float cs = ctxsum[bh * DH_ + d] * EPS_;
#pragma unroll
    for (int rg = 0; rg < 4; ++rg)
      ob[(size_t)(4 * lg + rg) * DH_ + d] =
          f2bf(RATIO_ * (cacc[db][rg] + cs) * dinv[rg]);
  }
}

// ----- Wo projection (wave-per-token, bf16 in) + residual + LN2 + FFN +
// residual, fused: lanes 0..7 finish one token each. grid B*N/32, 256 thr.
__global__ __launch_bounds__(256) void k_wo_ffn(
    const short* __restrict__ attn, const float* __restrict__ Wo,
    const float* __restrict__ bo, const float* __restrict__ g2,
    const float* __restrict__ be2, const float* __restrict__ W1,
    const float* __restrict__ bf1, const float* __restrict__ W2,
    const float* __restrict__ bf2, float* __restrict__ x) {
  __shared__ float wols[INNER_ * 3];
  __shared__ float bos[3];
  __shared__ float acc3[4][8][3];
  int t = threadIdx.x;
  for (int i = t; i < INNER_ * 3; i += 256) wols[i] = Wo[i];
  if (t < 3) bos[t] = bo[t];
  __syncthreads();
  int w = t >> 6, l = t & 63;
  int base = (blockIdx.x * 4 + w) * 8;
#pragma unroll
  for (int tt = 0; tt < 8; ++tt) {
    int token = base + tt;
    int b = token >> 12, n = token & 4095;
    float p0 = 0.f, p1 = 0.f, p2 = 0.f;
#pragma unroll
    for (int s = 0; s < 6; ++s) {
      int inner = l + 64 * s;
      int h = inner >> 7, dh = inner & 127;
      float a = bf2f(attn[(((size_t)(b * H_ + h)) * N_ + n) * DH_ + dh]);
      p0 = fmaf(a, wols[inner * 3 + 0], p0);
      p1 = fmaf(a, wols[inner * 3 + 1], p1);
      p2 = fmaf(a, wols[inner * 3 + 2], p2);
    }
#pragma unroll
    for (int off = 32; off; off >>= 1) {
      p0 += __shfl_down(p0, off);
      p1 += __shfl_down(p1, off);
      p2 += __shfl_down(p2, off);
    }
    if (l == 0) {
      acc3[w][tt][0] = p0 + bos[0];
      acc3[w][tt][1] = p1 + bos[1];
      acc3[w][tt][2] = p2 + bos[2];
    }
  }
  __syncthreads();
  if (l < 8) {
    int token = base + l;
    float x0 = x[(size_t)token * 3 + 0] + acc3[w][l][0];
    float x1 = x[(size_t)token * 3 + 1] + acc3[w][l][1];
    float x2 = x[(size_t)token * 3 + 2] + acc3[w][l][2];
    float mu = (x0 + x1 + x2) * (1.f / 3.f);
    float d0 = x0 - mu, d1 = x1 - mu, d2 = x2 - mu;
    float rs = rsqrtf((d0 * d0 + d1 * d1 + d2 * d2) * (1.f / 3.f) + 1e-5f);
    float h0 = d0 * rs * g2[0] + be2[0];
    float h1 = d1 * rs * g2[1] + be2[1];
    float h2 = d2 * rs * g2[2] + be2[2];
    float y0 = x0 + bf2[0], y1 = x1 + bf2[1], y2 = x2 + bf2[2];
#pragma unroll
    for (int tt = 0; tt < 12; ++tt) {
      float f = h0 * W1[tt] + h1 * W1[12 + tt] + h2 * W1[24 + tt] + bf1[tt];
      float g = 0.5f * f * (1.f + erff(f * 0.70710678118654752f));
      y0 += g * W2[tt * 3 + 0];
      y1 += g * W2[tt * 3 + 1];
      y2 += g * W2[tt * 3 + 2];
    }
    x[(size_t)token * 3 + 0] = y0;
    x[(size_t)token * 3 + 1] = y1;
    x[(size_t)token * 3 + 2] = y2;
  }
}

// ---------------------------------------------------------- decoder
__global__ void k_decode(const float* __restrict__ x, const float* __restrict__ dw,
                         const float* __restrict__ db, float* __restrict__ out) {
  int t = blockIdx.x * 256 + threadIdx.x;
  if (t < B_ * N_) {
    float l = x[(size_t)t * 3 + 0] * dw[0] + x[(size_t)t * 3 + 1] * dw[1] +
              x[(size_t)t * 3 + 2] * dw[2] + db[0];
    out[t] = 1.f / (1.f + expf(-l));
  }
}

// ================================================================ launch
extern "C" void kernel_launch(void* const* d_in, const int* in_sizes, int n_in,
                              void* d_out, int out_size, void* d_ws, size_t ws_size,
                              hipStream_t stream) {
  const float* x_in = (const float*)d_in[0];
  const float* Wq = (const float*)d_in[1];
  const float* Wk = (const float*)d_in[2];
  const float* Wv = (const float*)d_in[3];
  const float* Wo = (const float*)d_in[4];
  const float* bo = (const float*)d_in[5];
  const float* ln1g = (const float*)d_in[6];
  const float* ln1b = (const float*)d_in[7];
  const float* W1 = (const float*)d_in[8];
  const float* b1 = (const float*)d_in[9];
  const float* W2 = (const float*)d_in[10];
  const float* b2 = (const float*)d_in[11];
  const float* ln2g = (const float*)d_in[12];
  const float* ln2b = (const float*)d_in[13];
  const float* proj = (const float*)d_in[14];
  const float* dec_w = (const float*)d_in[15];
  const float* dec_b = (const float*)d_in[16];

  const size_t XB = (size_t)B_ * N_ * 3;
  const size_t QKV = (size_t)BH_ * N_ * DH_;       // 12582912
  const size_t CTX = (size_t)BH_ * MP_ * DH_;      // 1966080
  const size_t SS = (size_t)BH_ * MP_;

  char* p = (char*)d_ws;
  auto alloc = [&](size_t bytes) {
    char* r = p;
    p += (bytes + 255) & ~(size_t)255;
    return r;
  };
  float* xbuf = (float*)alloc(XB * 4);
  short* qb = (short*)alloc(QKV * 2);
  short* kb = (short*)alloc(QKV * 2);
  float* diag_k = (float*)alloc((size_t)BH_ * N_ * 4);
  short* pb = (short*)alloc((size_t)DEPTH_ * MP_ * DH_ * 2);
  short* vtp = (short*)alloc(QKV * 2);
  short* ctxtp = (short*)alloc(CTX * 2);
  // Cpart (31.5MB fp32) and o (25MB bf16) have disjoint lifetimes -> alias
  float* Cpart = (float*)alloc((size_t)4 * BH_ * MP_ * DH_ * 4);
  short* o = (short*)Cpart;
  float* spart = (float*)alloc(4 * SS * 4);
  float* cspart = (float*)alloc((size_t)BH_ * 20 * DH_ * 4);
  short* ksum_pb = (short*)alloc(SS * 2);
  float* vsp = (float*)alloc((size_t)BH_ * DH_ * 4);
  float* ctxsum = (float*)alloc((size_t)BH_ * DH_ * 4);
  float* ksumtot = (float*)alloc(BH_ * 4);
  float* bmx = (float*)alloc((size_t)4 * BH_ * 40 * 4);

  k_copy<<<(XB + 255) / 256, 256, 0, stream>>>(x_in, xbuf, (int)XB);
  k_projcvt<<<(DEPTH_ * MP_ * DH_ + 255) / 256, 256, 0, stream>>>(proj, pb);

  for (int i = 0; i < DEPTH_; ++i) {
    const short* pbL = pb + (size_t)i * MP_ * DH_;
    k_ln_qkv<<<B_ * N_ / 32, 384, 0, stream>>>(xbuf, Wq + (size_t)i * 3 * INNER_,
                                               Wk + (size_t)i * 3 * INNER_,
                                               Wv + (size_t)i * 3 * INNER_,
                                               ln1g + i * 3, ln1b + i * 3,
                                               qb, kb, vtp);
    k_dv<<<dim3(256, BH_), 256, 0, stream>>>(kb, vtp, diag_k, vsp);
    k_kp_ctx<<<dim3(4, 5, BH_), 512, 0, stream>>>(kb, vtp, pbL, diag_k,
                                                  Cpart, spart, bmx);
    k_fin_ctx<<<dim3(20, BH_), 256, 0, stream>>>(Cpart, vsp, bmx, ctxtp, cspart);
    k_fin2<<<BH_, 128, 0, stream>>>(cspart, spart, bmx, ctxsum, ksum_pb, ksumtot);
    k_q_attn<<<dim3(32, BH_), 512, 0, stream>>>(qb, pbL, ctxtp, ksum_pb,
                                                ctxsum, ksumtot, o);
    k_wo_ffn<<<B_ * N_ / 32, 256, 0, stream>>>(o, Wo + (size_t)i * INNER_ * 3,
                                               bo + i * 3, ln2g + i * 3, ln2b + i * 3,
                                               W1 + (size_t)i * 36, b1 + (size_t)i * 12,
                                               W2 + (size_t)i * 36, b2 + i * 3, xbuf);
  }
  k_decode<<<(B_ * N_ + 255) / 256, 256, 0, stream>>>(xbuf, dec_w, dec_b, (float*)d_out);
}

// Round 19
// 1000.741 us; speedup vs baseline: 1.1549x; 1.0327x over previous
//
#include <hip/hip_runtime.h>
#include <math.h>

// Performer (FAVOR+) forward, 6 layers. bf16 MFMA + global_load_lds staging.
// Round 19: T4 counted-vmcnt pipeline in k_q_attn (triple-buffered LDS,
// raw s_barrier + s_waitcnt vmcnt(2) -- next-chunk DMAs stay in flight
// across the barrier). Everything else identical to round-18 (1033 us).
// B=8 N=4096 DIM=3 H=3 DH=128 INNER=384 M=620(pad 640) FF=12
#define B_ 8
#define N_ 4096
#define H_ 3
#define DH_ 128
#define INNER_ 384
#define M_ 620
#define MP_ 640
#define DEPTH_ 6
#define BH_ 24

static constexpr float DN_ = 0.29730177875068026f;     // 128^-0.25
static constexpr float RATIO_ = 0.04016096644512494f;  // 620^-0.5
static constexpr float EPS_ = 1e-4f;

typedef __attribute__((ext_vector_type(8))) short short8;
typedef __attribute__((ext_vector_type(4))) float f32x4;

__device__ __forceinline__ short f2bf(float f) {
  union { float f; unsigned u; } x; x.f = f;
  unsigned r = x.u + 0x7FFF + ((x.u >> 16) & 1);
  return (short)(r >> 16);
}
__device__ __forceinline__ float bf2f(short s) {
  union { unsigned u; float f; } x; x.u = ((unsigned)(unsigned short)s) << 16;
  return x.f;
}
__device__ __forceinline__ float4 ldg4(const float* p) { return *(const float4*)p; }

// packed f32x2 -> bf16x2 (RNE), one VALU op
__device__ __forceinline__ unsigned cvtpk(float lo, float hi) {
  unsigned r;
  asm("v_cvt_pk_bf16_f32 %0, %1, %2" : "=v"(r) : "v"(lo), "v"(hi));
  return r;
}

// async global->LDS DMA, 16B per lane. LDS dest = uniform base + lane*16.
__device__ __forceinline__ void gl2lds(const void* g, void* l) {
  __builtin_amdgcn_global_load_lds(
      (const __attribute__((address_space(1))) void*)g,
      (__attribute__((address_space(3))) void*)l, 16, 0, 0);
}

// stage a 32-row x 256B tile, 8 waves (one DMA/lane). read back with:
// ofs = row*256 + (want ^ ((row&7)<<4))
__device__ __forceinline__ void stage_t256(const char* gbase, char* lds, int w, int l) {
  int row = w * 4 + (l >> 4);
  int col = ((l & 15) * 16) ^ ((row & 7) << 4);
  char* lp = lds + __builtin_amdgcn_readfirstlane(w << 10);
  gl2lds(gbase + row * 256 + col, lp);
}

// stage a 128-row x 64B tile (row stride growb bytes), 8 waves, swizzle
// sw64(d) = ((d ^ (d>>2)) & 3) << 4. read back: ofs = d*64 + (want ^ sw64(d))
__device__ __forceinline__ void stage_t64(const char* gbase, size_t growb, char* lds,
                                          int w, int l) {
  int d = w * 16 + (l >> 2);
  int swl = ((((l >> 2) ^ (l >> 4)) & 3) << 4);  // == sw64(d) for this lane
  int col = ((l & 3) * 16) ^ swl;
  char* lp = lds + __builtin_amdgcn_readfirstlane(w << 10);
  gl2lds(gbase + (size_t)d * growb + col, lp);
}

// ---------------------------------------------------------------- copy
__global__ void k_copy(const float* __restrict__ s, float* __restrict__ d, int n) {
  int i = blockIdx.x * 256 + threadIdx.x;
  if (i < n) d[i] = s[i];
}

// ------------------------------------------- proj -> bf16, padded to 640 rows
__global__ void k_projcvt(const float* __restrict__ proj, short* __restrict__ pb) {
  int i = blockIdx.x * 256 + threadIdx.x;
  if (i >= DEPTH_ * MP_ * DH_) return;
  int l = i / (MP_ * DH_);
  int rem = i - l * (MP_ * DH_);
  int m = rem >> 7, d = rem & 127;
  pb[i] = (m < M_) ? f2bf(proj[((size_t)l * M_ + m) * DH_ + d]) : (short)0;
}

// ---------- LN1 + QKV; 32 tokens/block; emits q,k row-major AND v directly
// transposed+pi-permuted into vtp (thread owns full n-row in registers).
__global__ __launch_bounds__(384) void k_ln_qkv(
    const float* __restrict__ x, const float* __restrict__ Wq,
    const float* __restrict__ Wk, const float* __restrict__ Wv,
    const float* __restrict__ g1, const float* __restrict__ b1,
    short* __restrict__ qb, short* __restrict__ kb, short* __restrict__ vtp) {
  __shared__ float xs[96];
  int c = threadIdx.x;
  int token0 = blockIdx.x * 32;
  int b = token0 >> 12, n0 = token0 & 4095;
  if (c < 96) xs[c] = x[(size_t)token0 * 3 + c];
  float wq0 = Wq[c], wq1 = Wq[INNER_ + c], wq2 = Wq[2 * INNER_ + c];
  float wk0 = Wk[c], wk1 = Wk[INNER_ + c], wk2 = Wk[2 * INNER_ + c];
  float wv0 = Wv[c], wv1 = Wv[INNER_ + c], wv2 = Wv[2 * INNER_ + c];
  float G0 = g1[0], G1 = g1[1], G2 = g1[2];
  float B0 = b1[0], B1 = b1[1], B2 = b1[2];
  int hh = c >> 7, dh = c & 127;
  size_t rowbase = ((size_t)(b * H_ + hh) * N_ + n0) * DH_ + dh;
  __syncthreads();
  short8 v8[4];
#pragma unroll
  for (int tt = 0; tt < 32; ++tt) {
    float x0 = xs[tt * 3], x1 = xs[tt * 3 + 1], x2 = xs[tt * 3 + 2];
    float mu = (x0 + x1 + x2) * (1.f / 3.f);
    float d0 = x0 - mu, d1 = x1 - mu, d2 = x2 - mu;
    float rs = rsqrtf((d0 * d0 + d1 * d1 + d2 * d2) * (1.f / 3.f) + 1e-5f);
    float h0 = d0 * rs * G0 + B0;
    float h1 = d1 * rs * G1 + B1;
    float h2 = d2 * rs * G2 + B2;
    qb[rowbase + (size_t)tt * DH_] = f2bf((h0 * wq0 + h1 * wq1 + h2 * wq2) * DN_);
    kb[rowbase + (size_t)tt * DH_] = f2bf((h0 * wk0 + h1 * wk1 + h2 * wk2) * DN_);
    const int p = ((tt >> 2) & 3) * 8 + ((tt >> 4) & 1) * 4 + (tt & 3);
    v8[p >> 3][p & 7] = f2bf(h0 * wv0 + h1 * wv1 + h2 * wv2);
  }
  short* dst = vtp + ((size_t)(b * H_ + hh) * DH_ + dh) * N_ + n0;
  *(short8*)dst = v8[0];
  *(short8*)(dst + 8) = v8[1];
  *(short8*)(dst + 16) = v8[2];
  *(short8*)(dst + 24) = v8[3];
}

// ---------- merged diag_k + vsum. grid (256, 24): x<128 -> vsum col d=x,
// x>=128 -> diag for n-tile x-128. 256 threads.
__global__ __launch_bounds__(256) void k_dv(
    const short* __restrict__ kb, const short* __restrict__ vtp,
    float* __restrict__ diag_k, float* __restrict__ vsp) {
  __shared__ float red[256];
  int xx = blockIdx.x, bh = blockIdx.y, t = threadIdx.x;
  if (xx < 128) {
    int d = xx;
    const short8* row = (const short8*)(vtp + ((size_t)bh * DH_ + d) * N_);
    short8 a = row[t * 2], b2 = row[t * 2 + 1];
    float s = 0.f;
#pragma unroll
    for (int j = 0; j < 8; ++j) s += bf2f(a[j]) + bf2f(b2[j]);
    red[t] = s;
    __syncthreads();
    for (int st = 128; st; st >>= 1) {
      if (t < st) red[t] += red[t + st];
      __syncthreads();
    }
    if (t == 0) vsp[bh * DH_ + d] = red[0];
  } else {
    int nt = xx - 128;
    int n = t >> 3, seg = t & 7;
    const short* src = kb + ((size_t)bh * N_ + nt * 32 + n) * DH_ + seg * 16;
    short8 a = *(const short8*)src;
    short8 b2 = *(const short8*)(src + 8);
    float s = 0.f;
#pragma unroll
    for (int j = 0; j < 8; ++j) {
      float va = bf2f(a[j]), vb = bf2f(b2[j]);
      s = fmaf(va, va, s);
      s = fmaf(vb, vb, s);
    }
    s += __shfl_down(s, 4);
    s += __shfl_down(s, 2);
    s += __shfl_down(s, 1);
    if (seg == 0) diag_k[(size_t)bh * N_ + nt * 32 + n] = 0.5f * s;
  }
}

// ------------- key features -> ctx partials (K,Vt via LDS double-buffer,
// PAIR-CHUNKED: 2 n-chunks per barrier period, 16 barriers total).
// grid (4 ns, 5 mt, 24 bh), 512 threads. Per-wave ONLINE max (exact).
__global__ __launch_bounds__(512) void k_kp_ctx(
    const short* __restrict__ kb, const short* __restrict__ vtp,
    const short* __restrict__ pb, const float* __restrict__ diag_k,
    float* __restrict__ Cpart, float* __restrict__ spart,
    float* __restrict__ bmx) {
  int ns = blockIdx.x, mt = blockIdx.y, bh = blockIdx.z;
  __shared__ __align__(16) char Ks[2][16384];
  __shared__ __align__(16) char Vts[2][16384];
  __shared__ float diag_s[1024];
  int t = threadIdx.x, w = t >> 6, l = t & 63, lr = l & 15, lg = l >> 4;
  {
    const float* dbase = diag_k + (size_t)bh * N_ + ns * 1024;
#pragma unroll
    for (int i = 0; i < 2; ++i) diag_s[t + i * 512] = dbase[t + i * 512];
  }
  int m0 = mt * 128 + w * 16;
  short8 bfr[4];
  {
    const short* pr = pb + (size_t)(m0 + lr) * DH_ + lg * 8;
#pragma unroll
    for (int ks = 0; ks < 4; ++ks) bfr[ks] = *(const short8*)(pr + ks * 32);
  }
  const char* kgb = (const char*)(kb + ((size_t)bh * N_ + ns * 1024) * DH_);
  const char* vgb = (const char*)(vtp + (size_t)bh * DH_ * N_ + ns * 1024);
  stage_t256(kgb, Ks[0], w, l);
  stage_t256(kgb + 32 * 256, Ks[0] + 8192, w, l);
  stage_t64(vgb, (size_t)N_ * 2, Vts[0], w, l);
  stage_t64(vgb + 64, (size_t)N_ * 2, Vts[0] + 8192, w, l);
  __syncthreads();
  f32x4 cacc[8];
#pragma unroll
  for (int db = 0; db < 8; ++db) cacc[db] = (f32x4){0.f, 0.f, 0.f, 0.f};
  float ksacc = 0.f;
  float bm = -INFINITY;  // wave-uniform running max of valid dd
  const bool mv = (m0 + lr) < M_;
  int xk = (lr & 7) << 4;
  int xv = ((lr ^ (lr >> 2)) & 3) << 4;  // sw64(db*16+lr), db-independent
  for (int pc = 0; pc < 16; ++pc) {
    int cur = pc & 1;
    if (pc < 15) {
      const char* kc = kgb + (size_t)(2 * pc + 2) * 32 * 256;
      stage_t256(kc, Ks[cur ^ 1], w, l);
      stage_t256(kc + 32 * 256, Ks[cur ^ 1] + 8192, w, l);
      const char* vc = vgb + (size_t)(2 * pc + 2) * 64;
      stage_t64(vc, (size_t)N_ * 2, Vts[cur ^ 1], w, l);
      stage_t64(vc + 64, (size_t)N_ * 2, Vts[cur ^ 1] + 8192, w, l);
    }
#pragma unroll
    for (int sub = 0; sub < 2; ++sub) {
      const char* KS = Ks[cur] + sub * 8192;
      const char* VS = Vts[cur] + sub * 8192;
      int n0 = (2 * pc + sub) * 32;
      f32x4 dd[2];
      __builtin_amdgcn_s_setprio(1);
#pragma unroll
      for (int nsub = 0; nsub < 2; ++nsub) {
        f32x4 acc = {0.f, 0.f, 0.f, 0.f};
#pragma unroll
        for (int ks = 0; ks < 4; ++ks)
          acc = __builtin_amdgcn_mfma_f32_16x16x32_bf16(
              *(const short8*)(KS + (nsub * 16 + lr) * 256 +
                               ((lg * 16 + ks * 64) ^ xk)),
              bfr[ks], acc, 0, 0, 0);
        dd[nsub] = acc;
      }
      __builtin_amdgcn_s_setprio(0);
      // wave-uniform online max over valid m (6-step xor reduce)
      float cm = -INFINITY;
      if (mv) {
#pragma unroll
        for (int nsub = 0; nsub < 2; ++nsub)
#pragma unroll
          for (int rg = 0; rg < 4; ++rg) cm = fmaxf(cm, dd[nsub][rg]);
      }
#pragma unroll
      for (int off = 1; off < 64; off <<= 1) cm = fmaxf(cm, __shfl_xor(cm, off));
      if (cm > bm) {  // wave-uniform
        float sc = __expf(bm - cm);  // 0 on first trigger
        bm = cm;
        ksacc *= sc;
#pragma unroll
        for (int db = 0; db < 8; ++db)
#pragma unroll
          for (int rg = 0; rg < 4; ++rg) cacc[db][rg] *= sc;
      }
      float ev[8];
#pragma unroll
      for (int nsub = 0; nsub < 2; ++nsub)
#pragma unroll
        for (int rg = 0; rg < 4; ++rg) {
          float e = __expf(dd[nsub][rg] - diag_s[n0 + nsub * 16 + 4 * lg + rg] - bm);
          ev[nsub * 4 + rg] = e;
          ksacc += e;
        }
      union { short8 s8; unsigned u[4]; } ea;
#pragma unroll
      for (int i = 0; i < 4; ++i) ea.u[i] = cvtpk(ev[2 * i], ev[2 * i + 1]);
      __builtin_amdgcn_s_setprio(1);
#pragma unroll
      for (int db = 0; db < 8; ++db)
        cacc[db] = __builtin_amdgcn_mfma_f32_16x16x32_bf16(
            ea.s8, *(const short8*)(VS + (db * 16 + lr) * 64 + ((lg * 16) ^ xv)),
            cacc[db], 0, 0, 0);
      __builtin_amdgcn_s_setprio(0);
    }
    __syncthreads();
  }
  float* Cp = Cpart + ((size_t)ns * BH_ + bh) * MP_ * DH_;
#pragma unroll
  for (int db = 0; db < 8; ++db) {
    int d = db * 16 + lr;
#pragma unroll
    for (int rg = 0; rg < 4; ++rg)
      Cp[(size_t)(m0 + 4 * lg + rg) * DH_ + d] = cacc[db][rg];
  }
  ksacc += __shfl_down(ksacc, 32);
  ksacc += __shfl_down(ksacc, 16);
  if (l < 16) spart[((size_t)ns * BH_ + bh) * MP_ + m0 + l] = ksacc;
  if (l == 0) bmx[((size_t)ns * BH_ + bh) * 40 + mt * 8 + w] = bm;
}

// ------ finalize ctx: weighted merge of 4 ns partials (exp(bm-mx)) + EPS*vsum,
// emit pi-permuted bf16 ctxtp tile + colsum partial. mx reduced inline.
// grid (20 mt, 24 bh), 256 threads.
__global__ __launch_bounds__(256) void k_fin_ctx(
    const float* __restrict__ Cpart, const float* __restrict__ vsp,
    const float* __restrict__ bmx,
    short* __restrict__ ctxtp, float* __restrict__ cspart) {
  int mt = blockIdx.x, bh = blockIdx.y;
  __shared__ float vsv[128];
  __shared__ short tile[128][40];
  __shared__ float redm[4];
  int t = threadIdx.x;
  if (t < 128) vsv[t] = vsp[bh * DH_ + t] * EPS_;
  float v = -INFINITY;
  if (t < 160) {
    int nsg = t / 40, g = t - nsg * 40;
    v = bmx[((size_t)nsg * BH_ + bh) * 40 + g];
  }
#pragma unroll
  for (int off = 32; off; off >>= 1) v = fmaxf(v, __shfl_xor(v, off));
  if ((t & 63) == 0) redm[t >> 6] = v;
  __syncthreads();
  float mxg = fmaxf(fmaxf(redm[0], redm[1]), fmaxf(redm[2], redm[3]));
  int r = t >> 3, seg = t & 7;
  int d0 = seg * 16;
  int m = mt * 32 + r;
  int p = ((r >> 2) & 3) * 8 + ((r >> 4) & 1) * 4 + (r & 3);
  const size_t ph = (size_t)BH_ * MP_ * DH_;
  const float* c0 = Cpart + (size_t)bh * MP_ * DH_ + (size_t)m * DH_ + d0;
  if (m < M_) {
    int g = m >> 4;
    float sc0 = __expf(bmx[((size_t)0 * BH_ + bh) * 40 + g] - mxg);
    float sc1 = __expf(bmx[((size_t)1 * BH_ + bh) * 40 + g] - mxg);
    float sc2 = __expf(bmx[((size_t)2 * BH_ + bh) * 40 + g] - mxg);
    float sc3 = __expf(bmx[((size_t)3 * BH_ + bh) * 40 + g] - mxg);
#pragma unroll
    for (int j4 = 0; j4 < 4; ++j4) {
      float4 a = ldg4(c0 + j4 * 4);
      float4 b = ldg4(c0 + ph + j4 * 4);
      float4 c = ldg4(c0 + 2 * ph + j4 * 4);
      float4 e = ldg4(c0 + 3 * ph + j4 * 4);
      float vals[4] = {sc0 * a.x + sc1 * b.x + sc2 * c.x + sc3 * e.x,
                       sc0 * a.y + sc1 * b.y + sc2 * c.y + sc3 * e.y,
                       sc0 * a.z + sc1 * b.z + sc2 * c.z + sc3 * e.z,
                       sc0 * a.w + sc1 * b.w + sc2 * c.w + sc3 * e.w};
#pragma unroll
      for (int j = 0; j < 4; ++j) {
        int d = d0 + j4 * 4 + j;
        tile[d][p] = f2bf(RATIO_ * (vals[j] + vsv[d]));
      }
    }
  } else {
#pragma unroll
    for (int j = 0; j < 16; ++j) tile[d0 + j][p] = 0;
  }
  __syncthreads();
  int d = t >> 1, half = t & 1;
  short* dst = ctxtp + ((size_t)bh * DH_ + d) * MP_ + mt * 32 + half * 16;
  short8 s0 = *(const short8*)&tile[d][half * 16];
  short8 s1 = *(const short8*)&tile[d][half * 16 + 8];
  *(short8*)dst = s0;
  *(short8*)(dst + 8) = s1;
  float cs = 0.f;
#pragma unroll
  for (int j = 0; j < 8; ++j) cs += bf2f(s0[j]) + bf2f(s1[j]);
  cs += __shfl_xor(cs, 1);
  if (half == 0) cspart[((size_t)bh * 20 + mt) * DH_ + d] = cs;
}

// ------ small finalize: ctxsum, weighted ksum merge (mx inline), ksum_pb
__global__ __launch_bounds__(128) void k_fin2(
    const float* __restrict__ cspart, const float* __restrict__ spart,
    const float* __restrict__ bmx,
    float* __restrict__ ctxsum, short* __restrict__ ksum_pb,
    float* __restrict__ ksumtot) {
  int bh = blockIdx.x, d = threadIdx.x;
  __shared__ float redm[2];
  float v = -INFINITY;
  for (int i = d; i < 160; i += 128) {
    int nsg = i / 40, g = i - nsg * 40;
    v = fmaxf(v, bmx[((size_t)nsg * BH_ + bh) * 40 + g]);
  }
#pragma unroll
  for (int off = 32; off; off >>= 1) v = fmaxf(v, __shfl_xor(v, off));
  if ((d & 63) == 0) redm[d >> 6] = v;
  float s = 0.f;
#pragma unroll
  for (int mt = 0; mt < 20; ++mt) s += cspart[((size_t)bh * 20 + mt) * DH_ + d];
  ctxsum[bh * DH_ + d] = s;
  __syncthreads();
  float mxg = fmaxf(redm[0], redm[1]);
  __shared__ float red[128];
  float kt = 0.f;
  for (int m = d; m < MP_; m += 128) {
    float ks = 0.f;
    if (m < M_) {
      size_t o = (size_t)bh * MP_ + m;
      size_t sh = (size_t)BH_ * MP_;
      int g = m >> 4;
      float s0 = __expf(bmx[((size_t)0 * BH_ + bh) * 40 + g] - mxg);
      float s1 = __expf(bmx[((size_t)1 * BH_ + bh) * 40 + g] - mxg);
      float s2 = __expf(bmx[((size_t)2 * BH_ + bh) * 40 + g] - mxg);
      float s3 = __expf(bmx[((size_t)3 * BH_ + bh) * 40 + g] - mxg);
      ks = RATIO_ * (s0 * spart[o] + s1 * spart[o + sh] + s2 * spart[o + 2 * sh] +
                     s3 * spart[o + 3 * sh] + EPS_ * (float)N_);
    }
    int r = m & 31;
    int p = ((r >> 2) & 3) * 8 + ((r >> 4) & 1) * 4 + (r & 3);
    ksum_pb[(size_t)bh * MP_ + (m & ~31) + p] = f2bf(ks);
    kt += ks;
  }
  red[d] = kt;
  __syncthreads();
  for (int st = 64; st > 0; st >>= 1) {
    if (d < st) red[d] += red[d + st];
    __syncthreads();
  }
  if (d == 0) ksumtot[bh] = red[0];
}

// -------- query side: online softmax (defer-rescale), den via MFMA,
// cvt_pk packing, bf16 output. TRIPLE-BUFFERED LDS + counted vmcnt:
// raw s_barrier, next-chunk DMAs stay in flight. grid (32 nt, 24 bh), 512 thr.
__global__ __launch_bounds__(512) void k_q_attn(
    const short* __restrict__ qb, const short* __restrict__ pb,
    const short* __restrict__ ctxtp, const short* __restrict__ ksum_pb,
    const float* __restrict__ ctxsum, const float* __restrict__ ksumtot,
    short* __restrict__ o) {
  int nt = blockIdx.x, bh = blockIdx.y;
  __shared__ __align__(16) char Pj[3][8192];
  __shared__ __align__(16) char Ct[3][8192];
  __shared__ __align__(16) short kslp[MP_];
  int t = threadIdx.x, w = t >> 6, l = t & 63, lr = l & 15, lg = l >> 4;
  if (t < MP_ / 8)
    ((short8*)kslp)[t] = ((const short8*)(ksum_pb + (size_t)bh * MP_))[t];
  const short* qr = qb + ((size_t)bh * N_ + nt * 128 + w * 16 + lr) * DH_ + lg * 8;
  short8 qfr[4];
#pragma unroll
  for (int ks = 0; ks < 4; ++ks) qfr[ks] = *(const short8*)(qr + ks * 32);
  // diag_q from fragments (bf16-consistent)
  float dq;
  {
    float s2 = 0.f;
#pragma unroll
    for (int ks = 0; ks < 4; ++ks)
#pragma unroll
      for (int j = 0; j < 8; ++j) {
        float v = bf2f(qfr[ks][j]);
        s2 = fmaf(v, v, s2);
      }
    s2 += __shfl_xor(s2, 16);
    s2 += __shfl_xor(s2, 32);
    dq = 0.5f * s2;
  }
  const char* cgb = (const char*)(ctxtp + (size_t)bh * DH_ * MP_);
  stage_t256((const char*)pb, Pj[0], w, l);
  stage_t64(cgb, (size_t)MP_ * 2, Ct[0], w, l);
  __syncthreads();  // full drain: kslp writes + chunk0 staged
  f32x4 cacc[8];
#pragma unroll
  for (int db = 0; db < 8; ++db) cacc[db] = (f32x4){0.f, 0.f, 0.f, 0.f};
  f32x4 dacc = {0.f, 0.f, 0.f, 0.f};
  float om = -INFINITY;
  int xk = (lr & 7) << 4;
  int xv = ((lr ^ (lr >> 2)) & 3) << 4;  // sw64(db*16+lr), db-independent
  int cur = 0, nxt = 1;
  for (int mc = 0; mc < 20; ++mc) {
    if (mc < 19) {
      stage_t256((const char*)(pb + (size_t)(mc + 1) * 32 * DH_), Pj[nxt], w, l);
      stage_t64(cgb + (size_t)(mc + 1) * 64, (size_t)MP_ * 2, Ct[nxt], w, l);
    }
    if (mc > 0) {
      // wait for THIS chunk's 2 DMAs (issued last iter); keep next 2 in flight
      if (mc < 19) asm volatile("s_waitcnt vmcnt(2)" ::: "memory");
      else         asm volatile("s_waitcnt vmcnt(0)" ::: "memory");
      __builtin_amdgcn_sched_barrier(0);
      __builtin_amdgcn_s_barrier();
      __builtin_amdgcn_sched_barrier(0);
    }
    int m0 = mc * 32;
    f32x4 qk[2];
    __builtin_amdgcn_s_setprio(1);
#pragma unroll
    for (int ms = 0; ms < 2; ++ms) {
      f32x4 acc = {0.f, 0.f, 0.f, 0.f};
#pragma unroll
      for (int ks = 0; ks < 4; ++ks)
        acc = __builtin_amdgcn_mfma_f32_16x16x32_bf16(
            *(const short8*)(Pj[cur] + (ms * 16 + lr) * 256 +
                             ((lg * 16 + ks * 64) ^ xk)),
            qfr[ks], acc, 0, 0, 0);
      qk[ms] = acc;
    }
    __builtin_amdgcn_s_setprio(0);
    // chunk row-max (rows n = lr; reduce across lg lane groups)
    float cm = -INFINITY;
#pragma unroll
    for (int ms = 0; ms < 2; ++ms)
#pragma unroll
      for (int rg = 0; rg < 4; ++rg) {
        int mg = m0 + ms * 16 + 4 * lg + rg;
        if (mg < M_) cm = fmaxf(cm, qk[ms][rg]);
      }
    cm = fmaxf(cm, __shfl_xor(cm, 16));
    cm = fmaxf(cm, __shfl_xor(cm, 32));
    // defer-rescale: exact (om stays the true running row max)
    if (__any(cm > om)) {
      float nm = fmaxf(om, cm);
      float sc = __expf(om - nm);  // 0 on first chunk
      om = nm;
      float scr[4];
#pragma unroll
      for (int rg = 0; rg < 4; ++rg) scr[rg] = __shfl(sc, 4 * lg + rg);
#pragma unroll
      for (int rg = 0; rg < 4; ++rg) dacc[rg] *= scr[rg];
#pragma unroll
      for (int db = 0; db < 8; ++db)
#pragma unroll
        for (int rg = 0; rg < 4; ++rg) cacc[db][rg] *= scr[rg];
    }
    float dqm = dq + om;
    float ev[8];
#pragma unroll
    for (int ms = 0; ms < 2; ++ms)
#pragma unroll
      for (int rg = 0; rg < 4; ++rg)
        ev[ms * 4 + rg] = __expf(qk[ms][rg] - dqm);
    union { short8 s8; unsigned u[4]; } ea;
#pragma unroll
    for (int i = 0; i < 4; ++i) ea.u[i] = cvtpk(ev[2 * i], ev[2 * i + 1]);
    __builtin_amdgcn_s_setprio(1);
    // den via MFMA: B-fragment = pi-permuted bf16 ksum slice (broadcast read)
    dacc = __builtin_amdgcn_mfma_f32_16x16x32_bf16(
        ea.s8, *(const short8*)&kslp[m0 + lg * 8], dacc, 0, 0, 0);
#pragma unroll
    for (int db = 0; db < 8; ++db)
      cacc[db] = __builtin_amdgcn_mfma_f32_16x16x32_bf16(
          ea.s8, *(const short8*)(Ct[cur] + (db * 16 + lr) * 64 + ((lg * 16) ^ xv)),
          cacc[db], 0, 0, 0);
    __builtin_amdgcn_s_setprio(0);
    cur = nxt;
    nxt = (nxt == 2) ? 0 : nxt + 1;
  }
  float kst = ksumtot[bh];
  float dinv[4];
#pragma unroll
  for (int rg = 0; rg < 4; ++rg)
    dinv[rg] = 1.f / (RATIO_ * (dacc[rg] + EPS_ * kst));
  short* ob = o + ((size_t)bh * N_ + nt * 128 + w * 16) * DH_;
#pragma unroll
  for (int db = 0; db < 8; ++db) {
    int d = db * 16 + lr;
    float cs = ctxsum[bh * DH_ + d] * EPS_;
#pragma unroll
    for (int rg = 0; rg < 4; ++rg)
      ob[(size_t)(4 * lg + rg) * DH_ + d] =
          f2bf(RATIO_ * (cacc[db][rg] + cs) * dinv[rg]);
  }
}

// ----- Wo projection (wave-per-token, bf16 in) + residual + LN2 + FFN +
// residual, fused: lanes 0..7 finish one token each. grid B*N/32, 256 thr.
__global__ __launch_bounds__(256) void k_wo_ffn(
    const short* __restrict__ attn, const float* __restrict__ Wo,
    const float* __restrict__ bo, const float* __restrict__ g2,
    const float* __restrict__ be2, const float* __restrict__ W1,
    const float* __restrict__ bf1, const float* __restrict__ W2,
    const float* __restrict__ bf2, float* __restrict__ x) {
  __shared__ float wols[INNER_ * 3];
  __shared__ float bos[3];
  __shared__ float acc3[4][8][3];
  int t = threadIdx.x;
  for (int i = t; i < INNER_ * 3; i += 256) wols[i] = Wo[i];
  if (t < 3) bos[t] = bo[t];
  __syncthreads();
  int w = t >> 6, l = t & 63;
  int base = (blockIdx.x * 4 + w) * 8;
#pragma unroll
  for (int tt = 0; tt < 8; ++tt) {
    int token = base + tt;
    int b = token >> 12, n = token & 4095;
    float p0 = 0.f, p1 = 0.f, p2 = 0.f;
#pragma unroll
    for (int s = 0; s < 6; ++s) {
      int inner = l + 64 * s;
      int h = inner >> 7, dh = inner & 127;
      float a = bf2f(attn[(((size_t)(b * H_ + h)) * N_ + n) * DH_ + dh]);
      p0 = fmaf(a, wols[inner * 3 + 0], p0);
      p1 = fmaf(a, wols[inner * 3 + 1], p1);
      p2 = fmaf(a, wols[inner * 3 + 2], p2);
    }
#pragma unroll
    for (int off = 32; off; off >>= 1) {
      p0 += __shfl_down(p0, off);
      p1 += __shfl_down(p1, off);
      p2 += __shfl_down(p2, off);
    }
    if (l == 0) {
      acc3[w][tt][0] = p0 + bos[0];
      acc3[w][tt][1] = p1 + bos[1];
      acc3[w][tt][2] = p2 + bos[2];
    }
  }
  __syncthreads();
  if (l < 8) {
    int token = base + l;
    float x0 = x[(size_t)token * 3 + 0] + acc3[w][l][0];
    float x1 = x[(size_t)token * 3 + 1] + acc3[w][l][1];
    float x2 = x[(size_t)token * 3 + 2] + acc3[w][l][2];
    float mu = (x0 + x1 + x2) * (1.f / 3.f);
    float d0 = x0 - mu, d1 = x1 - mu, d2 = x2 - mu;
    float rs = rsqrtf((d0 * d0 + d1 * d1 + d2 * d2) * (1.f / 3.f) + 1e-5f);
    float h0 = d0 * rs * g2[0] + be2[0];
    float h1 = d1 * rs * g2[1] + be2[1];
    float h2 = d2 * rs * g2[2] + be2[2];
    float y0 = x0 + bf2[0], y1 = x1 + bf2[1], y2 = x2 + bf2[2];
#pragma unroll
    for (int tt = 0; tt < 12; ++tt) {
      float f = h0 * W1[tt] + h1 * W1[12 + tt] + h2 * W1[24 + tt] + bf1[tt];
      float g = 0.5f * f * (1.f + erff(f * 0.70710678118654752f));
      y0 += g * W2[tt * 3 + 0];
      y1 += g * W2[tt * 3 + 1];
      y2 += g * W2[tt * 3 + 2];
    }
    x[(size_t)token * 3 + 0] = y0;
    x[(size_t)token * 3 + 1] = y1;
    x[(size_t)token * 3 + 2] = y2;
  }
}

// ---------------------------------------------------------- decoder
__global__ void k_decode(const float* __restrict__ x, const float* __restrict__ dw,
                         const float* __restrict__ db, float* __restrict__ out) {
  int t = blockIdx.x * 256 + threadIdx.x;
  if (t < B_ * N_) {
    float l = x[(size_t)t * 3 + 0] * dw[0] + x[(size_t)t * 3 + 1] * dw[1] +
              x[(size_t)t * 3 + 2] * dw[2] + db[0];
    out[t] = 1.f / (1.f + expf(-l));
  }
}

// ================================================================ launch
extern "C" void kernel_launch(void* const* d_in, const int* in_sizes, int n_in,
                              void* d_out, int out_size, void* d_ws, size_t ws_size,
                              hipStream_t stream) {
  const float* x_in = (const float*)d_in[0];
  const float* Wq = (const float*)d_in[1];
  const float* Wk = (const float*)d_in[2];
  const float* Wv = (const float*)d_in[3];
  const float* Wo = (const float*)d_in[4];
  const float* bo = (const float*)d_in[5];
  const float* ln1g = (const float*)d_in[6];
  const float* ln1b = (const float*)d_in[7];
  const float* W1 = (const float*)d_in[8];
  const float* b1 = (const float*)d_in[9];
  const float* W2 = (const float*)d_in[10];
  const float* b2 = (const float*)d_in[11];
  const float* ln2g = (const float*)d_in[12];
  const float* ln2b = (const float*)d_in[13];
  const float* proj = (const float*)d_in[14];
  const float* dec_w = (const float*)d_in[15];
  const float* dec_b = (const float*)d_in[16];

  const size_t XB = (size_t)B_ * N_ * 3;
  const size_t QKV = (size_t)BH_ * N_ * DH_;       // 12582912
  const size_t CTX = (size_t)BH_ * MP_ * DH_;      // 1966080
  const size_t SS = (size_t)BH_ * MP_;

  char* p = (char*)d_ws;
  auto alloc = [&](size_t bytes) {
    char* r = p;
    p += (bytes + 255) & ~(size_t)255;
    return r;
  };
  float* xbuf = (float*)alloc(XB * 4);
  short* qb = (short*)alloc(QKV * 2);
  short* kb = (short*)alloc(QKV * 2);
  float* diag_k = (float*)alloc((size_t)BH_ * N_ * 4);
  short* pb = (short*)alloc((size_t)DEPTH_ * MP_ * DH_ * 2);
  short* vtp = (short*)alloc(QKV * 2);
  short* ctxtp = (short*)alloc(CTX * 2);
  // Cpart (31.5MB fp32) and o (25MB bf16) have disjoint lifetimes -> alias
  float* Cpart = (float*)alloc((size_t)4 * BH_ * MP_ * DH_ * 4);
  short* o = (short*)Cpart;
  float* spart = (float*)alloc(4 * SS * 4);
  float* cspart = (float*)alloc((size_t)BH_ * 20 * DH_ * 4);
  short* ksum_pb = (short*)alloc(SS * 2);
  float* vsp = (float*)alloc((size_t)BH_ * DH_ * 4);
  float* ctxsum = (float*)alloc((size_t)BH_ * DH_ * 4);
  float* ksumtot = (float*)alloc(BH_ * 4);
  float* bmx = (float*)alloc((size_t)4 * BH_ * 40 * 4);

  k_copy<<<(XB + 255) / 256, 256, 0, stream>>>(x_in, xbuf, (int)XB);
  k_projcvt<<<(DEPTH_ * MP_ * DH_ + 255) / 256, 256, 0, stream>>>(proj, pb);

  for (int i = 0; i < DEPTH_; ++i) {
    const short* pbL = pb + (size_t)i * MP_ * DH_;
    k_ln_qkv<<<B_ * N_ / 32, 384, 0, stream>>>(xbuf, Wq + (size_t)i * 3 * INNER_,
                                               Wk + (size_t)i * 3 * INNER_,
                                               Wv + (size_t)i * 3 * INNER_,
                                               ln1g + i * 3, ln1b + i * 3,
                                               qb, kb, vtp);
    k_dv<<<dim3(256, BH_), 256, 0, stream>>>(kb, vtp, diag_k, vsp);
    k_kp_ctx<<<dim3(4, 5, BH_), 512, 0, stream>>>(kb, vtp, pbL, diag_k,
                                                  Cpart, spart, bmx);
    k_fin_ctx<<<dim3(20, BH_), 256, 0, stream>>>(Cpart, vsp, bmx, ctxtp, cspart);
    k_fin2<<<BH_, 128, 0, stream>>>(cspart, spart, bmx, ctxsum, ksum_pb, ksumtot);
    k_q_attn<<<dim3(32, BH_), 512, 0, stream>>>(qb, pbL, ctxtp, ksum_pb,
                                                ctxsum, ksumtot, o);
    k_wo_ffn<<<B_ * N_ / 32, 256, 0, stream>>>(o, Wo + (size_t)i * INNER_ * 3,
                                               bo + i * 3, ln2g + i * 3, ln2b + i * 3,
                                               W1 + (size_t)i * 36, b1 + (size_t)i * 12,
                                               W2 + (size_t)i * 36, b2 + i * 3, xbuf);
  }
  k_decode<<<(B_ * N_ + 255) / 256, 256, 0, stream>>>(xbuf, dec_w, dec_b, (float*)d_out);
}

// Round 20
// 986.696 us; speedup vs baseline: 1.1713x; 1.0142x over previous
//
#include <hip/hip_runtime.h>
#include <math.h>

// Performer (FAVOR+) forward, 6 layers. bf16 MFMA + global_load_lds staging.
// Round 20: T4 counted-vmcnt ported to k_kp_ctx (single-chunk TRIPLE-buffered
// LDS, raw s_barrier + s_waitcnt vmcnt(2); 52KB LDS -> 3 blocks/CU cap).
// k_q_attn keeps the round-19 pipeline (passed, 1001 us).
// B=8 N=4096 DIM=3 H=3 DH=128 INNER=384 M=620(pad 640) FF=12
#define B_ 8
#define N_ 4096
#define H_ 3
#define DH_ 128
#define INNER_ 384
#define M_ 620
#define MP_ 640
#define DEPTH_ 6
#define BH_ 24

static constexpr float DN_ = 0.29730177875068026f;     // 128^-0.25
static constexpr float RATIO_ = 0.04016096644512494f;  // 620^-0.5
static constexpr float EPS_ = 1e-4f;

typedef __attribute__((ext_vector_type(8))) short short8;
typedef __attribute__((ext_vector_type(4))) float f32x4;

__device__ __forceinline__ short f2bf(float f) {
  union { float f; unsigned u; } x; x.f = f;
  unsigned r = x.u + 0x7FFF + ((x.u >> 16) & 1);
  return (short)(r >> 16);
}
__device__ __forceinline__ float bf2f(short s) {
  union { unsigned u; float f; } x; x.u = ((unsigned)(unsigned short)s) << 16;
  return x.f;
}
__device__ __forceinline__ float4 ldg4(const float* p) { return *(const float4*)p; }

// packed f32x2 -> bf16x2 (RNE), one VALU op
__device__ __forceinline__ unsigned cvtpk(float lo, float hi) {
  unsigned r;
  asm("v_cvt_pk_bf16_f32 %0, %1, %2" : "=v"(r) : "v"(lo), "v"(hi));
  return r;
}

// async global->LDS DMA, 16B per lane. LDS dest = uniform base + lane*16.
__device__ __forceinline__ void gl2lds(const void* g, void* l) {
  __builtin_amdgcn_global_load_lds(
      (const __attribute__((address_space(1))) void*)g,
      (__attribute__((address_space(3))) void*)l, 16, 0, 0);
}

// stage a 32-row x 256B tile, 8 waves (one DMA/lane). read back with:
// ofs = row*256 + (want ^ ((row&7)<<4))
__device__ __forceinline__ void stage_t256(const char* gbase, char* lds, int w, int l) {
  int row = w * 4 + (l >> 4);
  int col = ((l & 15) * 16) ^ ((row & 7) << 4);
  char* lp = lds + __builtin_amdgcn_readfirstlane(w << 10);
  gl2lds(gbase + row * 256 + col, lp);
}

// stage a 128-row x 64B tile (row stride growb bytes), 8 waves, swizzle
// sw64(d) = ((d ^ (d>>2)) & 3) << 4. read back: ofs = d*64 + (want ^ sw64(d))
__device__ __forceinline__ void stage_t64(const char* gbase, size_t growb, char* lds,
                                          int w, int l) {
  int d = w * 16 + (l >> 2);
  int swl = ((((l >> 2) ^ (l >> 4)) & 3) << 4);  // == sw64(d) for this lane
  int col = ((l & 3) * 16) ^ swl;
  char* lp = lds + __builtin_amdgcn_readfirstlane(w << 10);
  gl2lds(gbase + (size_t)d * growb + col, lp);
}

// ---------------------------------------------------------------- copy
__global__ void k_copy(const float* __restrict__ s, float* __restrict__ d, int n) {
  int i = blockIdx.x * 256 + threadIdx.x;
  if (i < n) d[i] = s[i];
}

// ------------------------------------------- proj -> bf16, padded to 640 rows
__global__ void k_projcvt(const float* __restrict__ proj, short* __restrict__ pb) {
  int i = blockIdx.x * 256 + threadIdx.x;
  if (i >= DEPTH_ * MP_ * DH_) return;
  int l = i / (MP_ * DH_);
  int rem = i - l * (MP_ * DH_);
  int m = rem >> 7, d = rem & 127;
  pb[i] = (m < M_) ? f2bf(proj[((size_t)l * M_ + m) * DH_ + d]) : (short)0;
}

// ---------- LN1 + QKV; 32 tokens/block; emits q,k row-major AND v directly
// transposed+pi-permuted into vtp (thread owns full n-row in registers).
__global__ __launch_bounds__(384) void k_ln_qkv(
    const float* __restrict__ x, const float* __restrict__ Wq,
    const float* __restrict__ Wk, const float* __restrict__ Wv,
    const float* __restrict__ g1, const float* __restrict__ b1,
    short* __restrict__ qb, short* __restrict__ kb, short* __restrict__ vtp) {
  __shared__ float xs[96];
  int c = threadIdx.x;
  int token0 = blockIdx.x * 32;
  int b = token0 >> 12, n0 = token0 & 4095;
  if (c < 96) xs[c] = x[(size_t)token0 * 3 + c];
  float wq0 = Wq[c], wq1 = Wq[INNER_ + c], wq2 = Wq[2 * INNER_ + c];
  float wk0 = Wk[c], wk1 = Wk[INNER_ + c], wk2 = Wk[2 * INNER_ + c];
  float wv0 = Wv[c], wv1 = Wv[INNER_ + c], wv2 = Wv[2 * INNER_ + c];
  float G0 = g1[0], G1 = g1[1], G2 = g1[2];
  float B0 = b1[0], B1 = b1[1], B2 = b1[2];
  int hh = c >> 7, dh = c & 127;
  size_t rowbase = ((size_t)(b * H_ + hh) * N_ + n0) * DH_ + dh;
  __syncthreads();
  short8 v8[4];
#pragma unroll
  for (int tt = 0; tt < 32; ++tt) {
    float x0 = xs[tt * 3], x1 = xs[tt * 3 + 1], x2 = xs[tt * 3 + 2];
    float mu = (x0 + x1 + x2) * (1.f / 3.f);
    float d0 = x0 - mu, d1 = x1 - mu, d2 = x2 - mu;
    float rs = rsqrtf((d0 * d0 + d1 * d1 + d2 * d2) * (1.f / 3.f) + 1e-5f);
    float h0 = d0 * rs * G0 + B0;
    float h1 = d1 * rs * G1 + B1;
    float h2 = d2 * rs * G2 + B2;
    qb[rowbase + (size_t)tt * DH_] = f2bf((h0 * wq0 + h1 * wq1 + h2 * wq2) * DN_);
    kb[rowbase + (size_t)tt * DH_] = f2bf((h0 * wk0 + h1 * wk1 + h2 * wk2) * DN_);
    const int p = ((tt >> 2) & 3) * 8 + ((tt >> 4) & 1) * 4 + (tt & 3);
    v8[p >> 3][p & 7] = f2bf(h0 * wv0 + h1 * wv1 + h2 * wv2);
  }
  short* dst = vtp + ((size_t)(b * H_ + hh) * DH_ + dh) * N_ + n0;
  *(short8*)dst = v8[0];
  *(short8*)(dst + 8) = v8[1];
  *(short8*)(dst + 16) = v8[2];
  *(short8*)(dst + 24) = v8[3];
}

// ---------- merged diag_k + vsum. grid (256, 24): x<128 -> vsum col d=x,
// x>=128 -> diag for n-tile x-128. 256 threads.
__global__ __launch_bounds__(256) void k_dv(
    const short* __restrict__ kb, const short* __restrict__ vtp,
    float* __restrict__ diag_k, float* __restrict__ vsp) {
  __shared__ float red[256];
  int xx = blockIdx.x, bh = blockIdx.y, t = threadIdx.x;
  if (xx < 128) {
    int d = xx;
    const short8* row = (const short8*)(vtp + ((size_t)bh * DH_ + d) * N_);
    short8 a = row[t * 2], b2 = row[t * 2 + 1];
    float s = 0.f;
#pragma unroll
    for (int j = 0; j < 8; ++j) s += bf2f(a[j]) + bf2f(b2[j]);
    red[t] = s;
    __syncthreads();
    for (int st = 128; st; st >>= 1) {
      if (t < st) red[t] += red[t + st];
      __syncthreads();
    }
    if (t == 0) vsp[bh * DH_ + d] = red[0];
  } else {
    int nt = xx - 128;
    int n = t >> 3, seg = t & 7;
    const short* src = kb + ((size_t)bh * N_ + nt * 32 + n) * DH_ + seg * 16;
    short8 a = *(const short8*)src;
    short8 b2 = *(const short8*)(src + 8);
    float s = 0.f;
#pragma unroll
    for (int j = 0; j < 8; ++j) {
      float va = bf2f(a[j]), vb = bf2f(b2[j]);
      s = fmaf(va, va, s);
      s = fmaf(vb, vb, s);
    }
    s += __shfl_down(s, 4);
    s += __shfl_down(s, 2);
    s += __shfl_down(s, 1);
    if (seg == 0) diag_k[(size_t)bh * N_ + nt * 32 + n] = 0.5f * s;
  }
}

// ------------- key features -> ctx partials. TRIPLE-BUFFERED single-chunk
// pipeline with counted vmcnt (T4): raw s_barrier, next-chunk DMAs stay in
// flight. grid (4 ns, 5 mt, 24 bh), 512 threads. Per-wave ONLINE max (exact).
__global__ __launch_bounds__(512) void k_kp_ctx(
    const short* __restrict__ kb, const short* __restrict__ vtp,
    const short* __restrict__ pb, const float* __restrict__ diag_k,
    float* __restrict__ Cpart, float* __restrict__ spart,
    float* __restrict__ bmx) {
  int ns = blockIdx.x, mt = blockIdx.y, bh = blockIdx.z;
  __shared__ __align__(16) char Ks[3][8192];
  __shared__ __align__(16) char Vts[3][8192];
  __shared__ float diag_s[1024];
  int t = threadIdx.x, w = t >> 6, l = t & 63, lr = l & 15, lg = l >> 4;
  {
    const float* dbase = diag_k + (size_t)bh * N_ + ns * 1024;
#pragma unroll
    for (int i = 0; i < 2; ++i) diag_s[t + i * 512] = dbase[t + i * 512];
  }
  int m0 = mt * 128 + w * 16;
  short8 bfr[4];
  {
    const short* pr = pb + (size_t)(m0 + lr) * DH_ + lg * 8;
#pragma unroll
    for (int ks = 0; ks < 4; ++ks) bfr[ks] = *(const short8*)(pr + ks * 32);
  }
  const char* kgb = (const char*)(kb + ((size_t)bh * N_ + ns * 1024) * DH_);
  const char* vgb = (const char*)(vtp + (size_t)bh * DH_ * N_ + ns * 1024);
  stage_t256(kgb, Ks[0], w, l);
  stage_t64(vgb, (size_t)N_ * 2, Vts[0], w, l);
  __syncthreads();  // full drain: diag_s writes + chunk0 staged
  f32x4 cacc[8];
#pragma unroll
  for (int db = 0; db < 8; ++db) cacc[db] = (f32x4){0.f, 0.f, 0.f, 0.f};
  float ksacc = 0.f;
  float bm = -INFINITY;  // wave-uniform running max of valid dd
  const bool mv = (m0 + lr) < M_;
  int xk = (lr & 7) << 4;
  int xv = ((lr ^ (lr >> 2)) & 3) << 4;  // sw64(db*16+lr), db-independent
  int cur = 0, nxt = 1;
  for (int ch = 0; ch < 32; ++ch) {
    if (ch < 31) {
      stage_t256(kgb + (size_t)(ch + 1) * 32 * 256, Ks[nxt], w, l);
      stage_t64(vgb + (size_t)(ch + 1) * 64, (size_t)N_ * 2, Vts[nxt], w, l);
    }
    if (ch > 0) {
      // wait for THIS chunk's 2 DMAs (issued last iter); keep next 2 in flight
      if (ch < 31) asm volatile("s_waitcnt vmcnt(2)" ::: "memory");
      else         asm volatile("s_waitcnt vmcnt(0)" ::: "memory");
      __builtin_amdgcn_sched_barrier(0);
      __builtin_amdgcn_s_barrier();
      __builtin_amdgcn_sched_barrier(0);
    }
    const char* KS = Ks[cur];
    const char* VS = Vts[cur];
    int n0 = ch * 32;
    f32x4 dd[2];
    __builtin_amdgcn_s_setprio(1);
#pragma unroll
    for (int nsub = 0; nsub < 2; ++nsub) {
      f32x4 acc = {0.f, 0.f, 0.f, 0.f};
#pragma unroll
      for (int ks = 0; ks < 4; ++ks)
        acc = __builtin_amdgcn_mfma_f32_16x16x32_bf16(
            *(const short8*)(KS + (nsub * 16 + lr) * 256 +
                             ((lg * 16 + ks * 64) ^ xk)),
            bfr[ks], acc, 0, 0, 0);
      dd[nsub] = acc;
    }
    __builtin_amdgcn_s_setprio(0);
    // wave-uniform online max over valid m (6-step xor reduce)
    float cm = -INFINITY;
    if (mv) {
#pragma unroll
      for (int nsub = 0; nsub < 2; ++nsub)
#pragma unroll
        for (int rg = 0; rg < 4; ++rg) cm = fmaxf(cm, dd[nsub][rg]);
    }
#pragma unroll
    for (int off = 1; off < 64; off <<= 1) cm = fmaxf(cm, __shfl_xor(cm, off));
    if (cm > bm) {  // wave-uniform
      float sc = __expf(bm - cm);  // 0 on first trigger
      bm = cm;
      ksacc *= sc;
#pragma unroll
      for (int db = 0; db < 8; ++db)
#pragma unroll
        for (int rg = 0; rg < 4; ++rg) cacc[db][rg] *= sc;
    }
    float ev[8];
#pragma unroll
    for (int nsub = 0; nsub < 2; ++nsub)
#pragma unroll
      for (int rg = 0; rg < 4; ++rg) {
        float e = __expf(dd[nsub][rg] - diag_s[n0 + nsub * 16 + 4 * lg + rg] - bm);
        ev[nsub * 4 + rg] = e;
        ksacc += e;
      }
    union { short8 s8; unsigned u[4]; } ea;
#pragma unroll
    for (int i = 0; i < 4; ++i) ea.u[i] = cvtpk(ev[2 * i], ev[2 * i + 1]);
    __builtin_amdgcn_s_setprio(1);
#pragma unroll
    for (int db = 0; db < 8; ++db)
      cacc[db] = __builtin_amdgcn_mfma_f32_16x16x32_bf16(
          ea.s8, *(const short8*)(VS + (db * 16 + lr) * 64 + ((lg * 16) ^ xv)),
          cacc[db], 0, 0, 0);
    __builtin_amdgcn_s_setprio(0);
    cur = nxt;
    nxt = (nxt == 2) ? 0 : nxt + 1;
  }
  float* Cp = Cpart + ((size_t)ns * BH_ + bh) * MP_ * DH_;
#pragma unroll
  for (int db = 0; db < 8; ++db) {
    int d = db * 16 + lr;
#pragma unroll
    for (int rg = 0; rg < 4; ++rg)
      Cp[(size_t)(m0 + 4 * lg + rg) * DH_ + d] = cacc[db][rg];
  }
  ksacc += __shfl_down(ksacc, 32);
  ksacc += __shfl_down(ksacc, 16);
  if (l < 16) spart[((size_t)ns * BH_ + bh) * MP_ + m0 + l] = ksacc;
  if (l == 0) bmx[((size_t)ns * BH_ + bh) * 40 + mt * 8 + w] = bm;
}

// ------ finalize ctx: weighted merge of 4 ns partials (exp(bm-mx)) + EPS*vsum,
// emit pi-permuted bf16 ctxtp tile + colsum partial. mx reduced inline.
// grid (20 mt, 24 bh), 256 threads.
__global__ __launch_bounds__(256) void k_fin_ctx(
    const float* __restrict__ Cpart, const float* __restrict__ vsp,
    const float* __restrict__ bmx,
    short* __restrict__ ctxtp, float* __restrict__ cspart) {
  int mt = blockIdx.x, bh = blockIdx.y;
  __shared__ float vsv[128];
  __shared__ short tile[128][40];
  __shared__ float redm[4];
  int t = threadIdx.x;
  if (t < 128) vsv[t] = vsp[bh * DH_ + t] * EPS_;
  float v = -INFINITY;
  if (t < 160) {
    int nsg = t / 40, g = t - nsg * 40;
    v = bmx[((size_t)nsg * BH_ + bh) * 40 + g];
  }
#pragma unroll
  for (int off = 32; off; off >>= 1) v = fmaxf(v, __shfl_xor(v, off));
  if ((t & 63) == 0) redm[t >> 6] = v;
  __syncthreads();
  float mxg = fmaxf(fmaxf(redm[0], redm[1]), fmaxf(redm[2], redm[3]));
  int r = t >> 3, seg = t & 7;
  int d0 = seg * 16;
  int m = mt * 32 + r;
  int p = ((r >> 2) & 3) * 8 + ((r >> 4) & 1) * 4 + (r & 3);
  const size_t ph = (size_t)BH_ * MP_ * DH_;
  const float* c0 = Cpart + (size_t)bh * MP_ * DH_ + (size_t)m * DH_ + d0;
  if (m < M_) {
    int g = m >> 4;
    float sc0 = __expf(bmx[((size_t)0 * BH_ + bh) * 40 + g] - mxg);
    float sc1 = __expf(bmx[((size_t)1 * BH_ + bh) * 40 + g] - mxg);
    float sc2 = __expf(bmx[((size_t)2 * BH_ + bh) * 40 + g] - mxg);
    float sc3 = __expf(bmx[((size_t)3 * BH_ + bh) * 40 + g] - mxg);
#pragma unroll
    for (int j4 = 0; j4 < 4; ++j4) {
      float4 a = ldg4(c0 + j4 * 4);
      float4 b = ldg4(c0 + ph + j4 * 4);
      float4 c = ldg4(c0 + 2 * ph + j4 * 4);
      float4 e = ldg4(c0 + 3 * ph + j4 * 4);
      float vals[4] = {sc0 * a.x + sc1 * b.x + sc2 * c.x + sc3 * e.x,
                       sc0 * a.y + sc1 * b.y + sc2 * c.y + sc3 * e.y,
                       sc0 * a.z + sc1 * b.z + sc2 * c.z + sc3 * e.z,
                       sc0 * a.w + sc1 * b.w + sc2 * c.w + sc3 * e.w};
#pragma unroll
      for (int j = 0; j < 4; ++j) {
        int d = d0 + j4 * 4 + j;
        tile[d][p] = f2bf(RATIO_ * (vals[j] + vsv[d]));
      }
    }
  } else {
#pragma unroll
    for (int j = 0; j < 16; ++j) tile[d0 + j][p] = 0;
  }
  __syncthreads();
  int d = t >> 1, half = t & 1;
  short* dst = ctxtp + ((size_t)bh * DH_ + d) * MP_ + mt * 32 + half * 16;
  short8 s0 = *(const short8*)&tile[d][half * 16];
  short8 s1 = *(const short8*)&tile[d][half * 16 + 8];
  *(short8*)dst = s0;
  *(short8*)(dst + 8) = s1;
  float cs = 0.f;
#pragma unroll
  for (int j = 0; j < 8; ++j) cs += bf2f(s0[j]) + bf2f(s1[j]);
  cs += __shfl_xor(cs, 1);
  if (half == 0) cspart[((size_t)bh * 20 + mt) * DH_ + d] = cs;
}

// ------ small finalize: ctxsum, weighted ksum merge (mx inline), ksum_pb
__global__ __launch_bounds__(128) void k_fin2(
    const float* __restrict__ cspart, const float* __restrict__ spart,
    const float* __restrict__ bmx,
    float* __restrict__ ctxsum, short* __restrict__ ksum_pb,
    float* __restrict__ ksumtot) {
  int bh = blockIdx.x, d = threadIdx.x;
  __shared__ float redm[2];
  float v = -INFINITY;
  for (int i = d; i < 160; i += 128) {
    int nsg = i / 40, g = i - nsg * 40;
    v = fmaxf(v, bmx[((size_t)nsg * BH_ + bh) * 40 + g]);
  }
#pragma unroll
  for (int off = 32; off; off >>= 1) v = fmaxf(v, __shfl_xor(v, off));
  if ((d & 63) == 0) redm[d >> 6] = v;
  float s = 0.f;
#pragma unroll
  for (int mt = 0; mt < 20; ++mt) s += cspart[((size_t)bh * 20 + mt) * DH_ + d];
  ctxsum[bh * DH_ + d] = s;
  __syncthreads();
  float mxg = fmaxf(redm[0], redm[1]);
  __shared__ float red[128];
  float kt = 0.f;
  for (int m = d; m < MP_; m += 128) {
    float ks = 0.f;
    if (m < M_) {
      size_t o = (size_t)bh * MP_ + m;
      size_t sh = (size_t)BH_ * MP_;
      int g = m >> 4;
      float s0 = __expf(bmx[((size_t)0 * BH_ + bh) * 40 + g] - mxg);
      float s1 = __expf(bmx[((size_t)1 * BH_ + bh) * 40 + g] - mxg);
      float s2 = __expf(bmx[((size_t)2 * BH_ + bh) * 40 + g] - mxg);
      float s3 = __expf(bmx[((size_t)3 * BH_ + bh) * 40 + g] - mxg);
      ks = RATIO_ * (s0 * spart[o] + s1 * spart[o + sh] + s2 * spart[o + 2 * sh] +
                     s3 * spart[o + 3 * sh] + EPS_ * (float)N_);
    }
    int r = m & 31;
    int p = ((r >> 2) & 3) * 8 + ((r >> 4) & 1) * 4 + (r & 3);
    ksum_pb[(size_t)bh * MP_ + (m & ~31) + p] = f2bf(ks);
    kt += ks;
  }
  red[d] = kt;
  __syncthreads();
  for (int st = 64; st > 0; st >>= 1) {
    if (d < st) red[d] += red[d + st];
    __syncthreads();
  }
  if (d == 0) ksumtot[bh] = red[0];
}

// -------- query side: online softmax (defer-rescale), den via MFMA,
// cvt_pk packing, bf16 output. TRIPLE-BUFFERED LDS + counted vmcnt:
// raw s_barrier, next-chunk DMAs stay in flight. grid (32 nt, 24 bh), 512 thr.
__global__ __launch_bounds__(512) void k_q_attn(
    const short* __restrict__ qb, const short* __restrict__ pb,
    const short* __restrict__ ctxtp, const short* __restrict__ ksum_pb,
    const float* __restrict__ ctxsum, const float* __restrict__ ksumtot,
    short* __restrict__ o) {
  int nt = blockIdx.x, bh = blockIdx.y;
  __shared__ __align__(16) char Pj[3][8192];
  __shared__ __align__(16) char Ct[3][8192];
  __shared__ __align__(16) short kslp[MP_];
  int t = threadIdx.x, w = t >> 6, l = t & 63, lr = l & 15, lg = l >> 4;
  if (t < MP_ / 8)
    ((short8*)kslp)[t] = ((const short8*)(ksum_pb + (size_t)bh * MP_))[t];
  const short* qr = qb + ((size_t)bh * N_ + nt * 128 + w * 16 + lr) * DH_ + lg * 8;
  short8 qfr[4];
#pragma unroll
  for (int ks = 0; ks < 4; ++ks) qfr[ks] = *(const short8*)(qr + ks * 32);
  // diag_q from fragments (bf16-consistent)
  float dq;
  {
    float s2 = 0.f;
#pragma unroll
    for (int ks = 0; ks < 4; ++ks)
#pragma unroll
      for (int j = 0; j < 8; ++j) {
        float v = bf2f(qfr[ks][j]);
        s2 = fmaf(v, v, s2);
      }
    s2 += __shfl_xor(s2, 16);
    s2 += __shfl_xor(s2, 32);
    dq = 0.5f * s2;
  }
  const char* cgb = (const char*)(ctxtp + (size_t)bh * DH_ * MP_);
  stage_t256((const char*)pb, Pj[0], w, l);
  stage_t64(cgb, (size_t)MP_ * 2, Ct[0], w, l);
  __syncthreads();  // full drain: kslp writes + chunk0 staged
  f32x4 cacc[8];
#pragma unroll
  for (int db = 0; db < 8; ++db) cacc[db] = (f32x4){0.f, 0.f, 0.f, 0.f};
  f32x4 dacc = {0.f, 0.f, 0.f, 0.f};
  float om = -INFINITY;
  int xk = (lr & 7) << 4;
  int xv = ((lr ^ (lr >> 2)) & 3) << 4;  // sw64(db*16+lr), db-independent
  int cur = 0, nxt = 1;
  for (int mc = 0; mc < 20; ++mc) {
    if (mc < 19) {
      stage_t256((const char*)(pb + (size_t)(mc + 1) * 32 * DH_), Pj[nxt], w, l);
      stage_t64(cgb + (size_t)(mc + 1) * 64, (size_t)MP_ * 2, Ct[nxt], w, l);
    }
    if (mc > 0) {
      // wait for THIS chunk's 2 DMAs (issued last iter); keep next 2 in flight
      if (mc < 19) asm volatile("s_waitcnt vmcnt(2)" ::: "memory");
      else         asm volatile("s_waitcnt vmcnt(0)" ::: "memory");
      __builtin_amdgcn_sched_barrier(0);
      __builtin_amdgcn_s_barrier();
      __builtin_amdgcn_sched_barrier(0);
    }
    int m0 = mc * 32;
    f32x4 qk[2];
    __builtin_amdgcn_s_setprio(1);
#pragma unroll
    for (int ms = 0; ms < 2; ++ms) {
      f32x4 acc = {0.f, 0.f, 0.f, 0.f};
#pragma unroll
      for (int ks = 0; ks < 4; ++ks)
        acc = __builtin_amdgcn_mfma_f32_16x16x32_bf16(
            *(const short8*)(Pj[cur] + (ms * 16 + lr) * 256 +
                             ((lg * 16 + ks * 64) ^ xk)),
            qfr[ks], acc, 0, 0, 0);
      qk[ms] = acc;
    }
    __builtin_amdgcn_s_setprio(0);
    // chunk row-max (rows n = lr; reduce across lg lane groups)
    float cm = -INFINITY;
#pragma unroll
    for (int ms = 0; ms < 2; ++ms)
#pragma unroll
      for (int rg = 0; rg < 4; ++rg) {
        int mg = m0 + ms * 16 + 4 * lg + rg;
        if (mg < M_) cm = fmaxf(cm, qk[ms][rg]);
      }
    cm = fmaxf(cm, __shfl_xor(cm, 16));
    cm = fmaxf(cm, __shfl_xor(cm, 32));
    // defer-rescale: exact (om stays the true running row max)
    if (__any(cm > om)) {
      float nm = fmaxf(om, cm);
      float sc = __expf(om - nm);  // 0 on first chunk
      om = nm;
      float scr[4];
#pragma unroll
      for (int rg = 0; rg < 4; ++rg) scr[rg] = __shfl(sc, 4 * lg + rg);
#pragma unroll
      for (int rg = 0; rg < 4; ++rg) dacc[rg] *= scr[rg];
#pragma unroll
      for (int db = 0; db < 8; ++db)
#pragma unroll
        for (int rg = 0; rg < 4; ++rg) cacc[db][rg] *= scr[rg];
    }
    float dqm = dq + om;
    float ev[8];
#pragma unroll
    for (int ms = 0; ms < 2; ++ms)
#pragma unroll
      for (int rg = 0; rg < 4; ++rg)
        ev[ms * 4 + rg] = __expf(qk[ms][rg] - dqm);
    union { short8 s8; unsigned u[4]; } ea;
#pragma unroll
    for (int i = 0; i < 4; ++i) ea.u[i] = cvtpk(ev[2 * i], ev[2 * i + 1]);
    __builtin_amdgcn_s_setprio(1);
    // den via MFMA: B-fragment = pi-permuted bf16 ksum slice (broadcast read)
    dacc = __builtin_amdgcn_mfma_f32_16x16x32_bf16(
        ea.s8, *(const short8*)&kslp[m0 + lg * 8], dacc, 0, 0, 0);
#pragma unroll
    for (int db = 0; db < 8; ++db)
      cacc[db] = __builtin_amdgcn_mfma_f32_16x16x32_bf16(
          ea.s8, *(const short8*)(Ct[cur] + (db * 16 + lr) * 64 + ((lg * 16) ^ xv)),
          cacc[db], 0, 0, 0);
    __builtin_amdgcn_s_setprio(0);
    cur = nxt;
    nxt = (nxt == 2) ? 0 : nxt + 1;
  }
  float kst = ksumtot[bh];
  float dinv[4];
#pragma unroll
  for (int rg = 0; rg < 4; ++rg)
    dinv[rg] = 1.f / (RATIO_ * (dacc[rg] + EPS_ * kst));
  short* ob = o + ((size_t)bh * N_ + nt * 128 + w * 16) * DH_;
#pragma unroll
  for (int db = 0; db < 8; ++db) {
    int d = db * 16 + lr;
    float cs = ctxsum[bh * DH_ + d] * EPS_;
#pragma unroll
    for (int rg = 0; rg < 4; ++rg)
      ob[(size_t)(4 * lg + rg) * DH_ + d] =
          f2bf(RATIO_ * (cacc[db][rg] + cs) * dinv[rg]);
  }
}

// ----- Wo projection (wave-per-token, bf16 in) + residual + LN2 + FFN +
// residual, fused: lanes 0..7 finish one token each. grid B*N/32, 256 thr.
__global__ __launch_bounds__(256) void k_wo_ffn(
    const short* __restrict__ attn, const float* __restrict__ Wo,
    const float* __restrict__ bo, const float* __restrict__ g2,
    const float* __restrict__ be2, const float* __restrict__ W1,
    const float* __restrict__ bf1, const float* __restrict__ W2,
    const float* __restrict__ bf2, float* __restrict__ x) {
  __shared__ float wols[INNER_ * 3];
  __shared__ float bos[3];
  __shared__ float acc3[4][8][3];
  int t = threadIdx.x;
  for (int i = t; i < INNER_ * 3; i += 256) wols[i] = Wo[i];
  if (t < 3) bos[t] = bo[t];
  __syncthreads();
  int w = t >> 6, l = t & 63;
  int base = (blockIdx.x * 4 + w) * 8;
#pragma unroll
  for (int tt = 0; tt < 8; ++tt) {
    int token = base + tt;
    int b = token >> 12, n = token & 4095;
    float p0 = 0.f, p1 = 0.f, p2 = 0.f;
#pragma unroll
    for (int s = 0; s < 6; ++s) {
      int inner = l + 64 * s;
      int h = inner >> 7, dh = inner & 127;
      float a = bf2f(attn[(((size_t)(b * H_ + h)) * N_ + n) * DH_ + dh]);
      p0 = fmaf(a, wols[inner * 3 + 0], p0);
      p1 = fmaf(a, wols[inner * 3 + 1], p1);
      p2 = fmaf(a, wols[inner * 3 + 2], p2);
    }
#pragma unroll
    for (int off = 32; off; off >>= 1) {
      p0 += __shfl_down(p0, off);
      p1 += __shfl_down(p1, off);
      p2 += __shfl_down(p2, off);
    }
    if (l == 0) {
      acc3[w][tt][0] = p0 + bos[0];
      acc3[w][tt][1] = p1 + bos[1];
      acc3[w][tt][2] = p2 + bos[2];
    }
  }
  __syncthreads();
  if (l < 8) {
    int token = base + l;
    float x0 = x[(size_t)token * 3 + 0] + acc3[w][l][0];
    float x1 = x[(size_t)token * 3 + 1] + acc3[w][l][1];
    float x2 = x[(size_t)token * 3 + 2] + acc3[w][l][2];
    float mu = (x0 + x1 + x2) * (1.f / 3.f);
    float d0 = x0 - mu, d1 = x1 - mu, d2 = x2 - mu;
    float rs = rsqrtf((d0 * d0 + d1 * d1 + d2 * d2) * (1.f / 3.f) + 1e-5f);
    float h0 = d0 * rs * g2[0] + be2[0];
    float h1 = d1 * rs * g2[1] + be2[1];
    float h2 = d2 * rs * g2[2] + be2[2];
    float y0 = x0 + bf2[0], y1 = x1 + bf2[1], y2 = x2 + bf2[2];
#pragma unroll
    for (int tt = 0; tt < 12; ++tt) {
      float f = h0 * W1[tt] + h1 * W1[12 + tt] + h2 * W1[24 + tt] + bf1[tt];
      float g = 0.5f * f * (1.f + erff(f * 0.70710678118654752f));
      y0 += g * W2[tt * 3 + 0];
      y1 += g * W2[tt * 3 + 1];
      y2 += g * W2[tt * 3 + 2];
    }
    x[(size_t)token * 3 + 0] = y0;
    x[(size_t)token * 3 + 1] = y1;
    x[(size_t)token * 3 + 2] = y2;
  }
}

// ---------------------------------------------------------- decoder
__global__ void k_decode(const float* __restrict__ x, const float* __restrict__ dw,
                         const float* __restrict__ db, float* __restrict__ out) {
  int t = blockIdx.x * 256 + threadIdx.x;
  if (t < B_ * N_) {
    float l = x[(size_t)t * 3 + 0] * dw[0] + x[(size_t)t * 3 + 1] * dw[1] +
              x[(size_t)t * 3 + 2] * dw[2] + db[0];
    out[t] = 1.f / (1.f + expf(-l));
  }
}

// ================================================================ launch
extern "C" void kernel_launch(void* const* d_in, const int* in_sizes, int n_in,
                              void* d_out, int out_size, void* d_ws, size_t ws_size,
                              hipStream_t stream) {
  const float* x_in = (const float*)d_in[0];
  const float* Wq = (const float*)d_in[1];
  const float* Wk = (const float*)d_in[2];
  const float* Wv = (const float*)d_in[3];
  const float* Wo = (const float*)d_in[4];
  const float* bo = (const float*)d_in[5];
  const float* ln1g = (const float*)d_in[6];
  const float* ln1b = (const float*)d_in[7];
  const float* W1 = (const float*)d_in[8];
  const float* b1 = (const float*)d_in[9];
  const float* W2 = (const float*)d_in[10];
  const float* b2 = (const float*)d_in[11];
  const float* ln2g = (const float*)d_in[12];
  const float* ln2b = (const float*)d_in[13];
  const float* proj = (const float*)d_in[14];
  const float* dec_w = (const float*)d_in[15];
  const float* dec_b = (const float*)d_in[16];

  const size_t XB = (size_t)B_ * N_ * 3;
  const size_t QKV = (size_t)BH_ * N_ * DH_;       // 12582912
  const size_t CTX = (size_t)BH_ * MP_ * DH_;      // 1966080
  const size_t SS = (size_t)BH_ * MP_;

  char* p = (char*)d_ws;
  auto alloc = [&](size_t bytes) {
    char* r = p;
    p += (bytes + 255) & ~(size_t)255;
    return r;
  };
  float* xbuf = (float*)alloc(XB * 4);
  short* qb = (short*)alloc(QKV * 2);
  short* kb = (short*)alloc(QKV * 2);
  float* diag_k = (float*)alloc((size_t)BH_ * N_ * 4);
  short* pb = (short*)alloc((size_t)DEPTH_ * MP_ * DH_ * 2);
  short* vtp = (short*)alloc(QKV * 2);
  short* ctxtp = (short*)alloc(CTX * 2);
  // Cpart (31.5MB fp32) and o (25MB bf16) have disjoint lifetimes -> alias
  float* Cpart = (float*)alloc((size_t)4 * BH_ * MP_ * DH_ * 4);
  short* o = (short*)Cpart;
  float* spart = (float*)alloc(4 * SS * 4);
  float* cspart = (float*)alloc((size_t)BH_ * 20 * DH_ * 4);
  short* ksum_pb = (short*)alloc(SS * 2);
  float* vsp = (float*)alloc((size_t)BH_ * DH_ * 4);
  float* ctxsum = (float*)alloc((size_t)BH_ * DH_ * 4);
  float* ksumtot = (float*)alloc(BH_ * 4);
  float* bmx = (float*)alloc((size_t)4 * BH_ * 40 * 4);

  k_copy<<<(XB + 255) / 256, 256, 0, stream>>>(x_in, xbuf, (int)XB);
  k_projcvt<<<(DEPTH_ * MP_ * DH_ + 255) / 256, 256, 0, stream>>>(proj, pb);

  for (int i = 0; i < DEPTH_; ++i) {
    const short* pbL = pb + (size_t)i * MP_ * DH_;
    k_ln_qkv<<<B_ * N_ / 32, 384, 0, stream>>>(xbuf, Wq + (size_t)i * 3 * INNER_,
                                               Wk + (size_t)i * 3 * INNER_,
                                               Wv + (size_t)i * 3 * INNER_,
                                               ln1g + i * 3, ln1b + i * 3,
                                               qb, kb, vtp);
    k_dv<<<dim3(256, BH_), 256, 0, stream>>>(kb, vtp, diag_k, vsp);
    k_kp_ctx<<<dim3(4, 5, BH_), 512, 0, stream>>>(kb, vtp, pbL, diag_k,
                                                  Cpart, spart, bmx);
    k_fin_ctx<<<dim3(20, BH_), 256, 0, stream>>>(Cpart, vsp, bmx, ctxtp, cspart);
    k_fin2<<<BH_, 128, 0, stream>>>(cspart, spart, bmx, ctxsum, ksum_pb, ksumtot);
    k_q_attn<<<dim3(32, BH_), 512, 0, stream>>>(qb, pbL, ctxtp, ksum_pb,
                                                ctxsum, ksumtot, o);
    k_wo_ffn<<<B_ * N_ / 32, 256, 0, stream>>>(o, Wo + (size_t)i * INNER_ * 3,
                                               bo + i * 3, ln2g + i * 3, ln2b + i * 3,
                                               W1 + (size_t)i * 36, b1 + (size_t)i * 12,
                                               W2 + (size_t)i * 36, b2 + i * 3, xbuf);
  }
  k_decode<<<(B_ * N_ + 255) / 256, 256, 0, stream>>>(xbuf, dec_w, dec_b, (float*)d_out);
}